// Round 8
// baseline (1411.456 us; speedup 1.0000x reference)
//
#include <hip/hip_runtime.h>
#include <hip/hip_bf16.h>

// ---------------------------------------------------------------------------
// PUSCH neural detector: 4 stacked ConvLSTM layers on [B=2,T=14,H=1536,W=1].
// 3x3 conv degenerates to width-3 conv along H (kw=1 slice). f32 throughout.
// Round 8: per-layer FUSED scan kernel (14 steps in one launch) with
// neighbor spin-flag sync; h interior in LDS, c in registers, edge rows via
// device-scope atomics. GEMM unchanged.
// ---------------------------------------------------------------------------

#define BB   2
#define TT   14
#define LL   1536
#define CINR 297
#define CINP 304
#define NSTRIP 96                 // LL / 16
#define NBLK  (BB * NSTRIP)       // 192 scan blocks

// ---- workspace layout (units: f32 elements) -------------------------------
static constexpr size_t SZ_WXIN  = (size_t)3*CINP*256;
static constexpr size_t SZ_WH64  = (size_t)3*64*256;
static constexpr size_t SZ_WXOUT = (size_t)3*64*128;
static constexpr size_t SZ_WHOUT = (size_t)3*32*128;

static constexpr size_t OFF_WXIN  = 0;
static constexpr size_t OFF_WHIN  = OFF_WXIN  + SZ_WXIN;
static constexpr size_t OFF_WXR0  = OFF_WHIN  + SZ_WH64;
static constexpr size_t OFF_WHR0  = OFF_WXR0  + SZ_WH64;
static constexpr size_t OFF_WXR1  = OFF_WHR0  + SZ_WH64;
static constexpr size_t OFF_WHR1  = OFF_WXR1  + SZ_WH64;
static constexpr size_t OFF_WXOUT = OFF_WHR1  + SZ_WH64;
static constexpr size_t OFF_WHOUT = OFF_WXOUT + SZ_WXOUT;
static constexpr size_t OFF_BIN   = OFF_WHOUT + SZ_WHOUT;
static constexpr size_t OFF_BR0   = OFF_BIN + 256;
static constexpr size_t OFF_BR1   = OFF_BR0 + 256;
static constexpr size_t OFF_BOUT  = OFF_BR1 + 256;
static constexpr size_t PREP_TOTAL = OFF_BOUT + 128;

static constexpr size_t OFF_Z0  = 524288;                 // f32 [28][1536][304]
static constexpr size_t SZ_Z0   = (size_t)BB*TT*LL*CINP;
static constexpr size_t OFF_XZ  = OFF_Z0 + SZ_Z0;         // f32 [28][1536][256]
static constexpr size_t SZ_XZ   = (size_t)BB*TT*LL*256;
static constexpr size_t OFF_SEQ = OFF_XZ + SZ_XZ;         // f32 [28][1536][64]
static constexpr size_t SZ_SEQ  = (size_t)BB*TT*LL*64;
static constexpr size_t OFF_EDGE = OFF_SEQ + SZ_SEQ;      // [2][NBLK][2][64]
static constexpr size_t SZ_EDGE  = (size_t)2*NBLK*2*64;
static constexpr size_t OFF_FLAGS = OFF_EDGE + SZ_EDGE;   // NBLK ints
// ~110 MB total

__device__ __forceinline__ float hsig(float x) {
    return fminf(fmaxf(0.2f * x + 0.5f, 0.0f), 1.0f);
}

// ---------------------------------------------------------------------------
// prep_weights. Wx stored [k][ci][co'] with co' = f*4+g (gate-interleaved).
// Wh stored transposed [k][ci][f][gate4]. Biases permuted to co'.
// ---------------------------------------------------------------------------
__device__ __forceinline__ float wx_midP(const float* src, int Cin, int N, int idx) {
    int k = idx / (Cin * N); int r = idx - k * (Cin * N);
    int ci = r / N; int cop = r - ci * N;
    int Fo = N >> 2;
    int f = cop >> 2, g = cop & 3;
    return src[((size_t)(k * 3 + 1) * Cin + ci) * N + g * Fo + f];
}
__device__ __forceinline__ float wh_midT(const float* src, int F_, int idx) {
    int N4 = 4 * F_;
    int k = idx / (F_ * N4); int r = idx - k * (F_ * N4);
    int ci = r / N4; int fg = r - ci * N4;
    int f = fg >> 2, g = fg & 3;
    return src[((size_t)(k * 3 + 1) * F_ + ci) * N4 + g * F_ + f];
}

__global__ __launch_bounds__(256)
void prep_weights_kernel(const float* wx_in, const float* wh_in, const float* b_in,
                         const float* wx_r0, const float* wh_r0, const float* b_r0,
                         const float* wx_r1, const float* wh_r1, const float* b_r1,
                         const float* wx_out, const float* wh_out, const float* b_out,
                         float* __restrict__ ws)
{
    int idx = blockIdx.x * 256 + threadIdx.x;
    if (idx < (int)SZ_WXIN) {
        int k = idx / (CINP * 256); int r = idx - k * (CINP * 256);
        int ci = r >> 8; int cop = r & 255;
        float v = 0.0f;
        if (ci < CINR) {
            int f = cop >> 2, g = cop & 3;
            v = wx_in[((size_t)(k * 3 + 1) * CINR + ci) * 256 + g * 64 + f];
        }
        ws[OFF_WXIN + idx] = v; return;
    }
    idx -= (int)SZ_WXIN;
    if (idx < (int)SZ_WH64) { ws[OFF_WHIN + idx] = wh_midT(wh_in, 64, idx); return; }
    idx -= (int)SZ_WH64;
    if (idx < (int)SZ_WH64) { ws[OFF_WXR0 + idx] = wx_midP(wx_r0, 64, 256, idx); return; }
    idx -= (int)SZ_WH64;
    if (idx < (int)SZ_WH64) { ws[OFF_WHR0 + idx] = wh_midT(wh_r0, 64, idx); return; }
    idx -= (int)SZ_WH64;
    if (idx < (int)SZ_WH64) { ws[OFF_WXR1 + idx] = wx_midP(wx_r1, 64, 256, idx); return; }
    idx -= (int)SZ_WH64;
    if (idx < (int)SZ_WH64) { ws[OFF_WHR1 + idx] = wh_midT(wh_r1, 64, idx); return; }
    idx -= (int)SZ_WH64;
    if (idx < (int)SZ_WXOUT) { ws[OFF_WXOUT + idx] = wx_midP(wx_out, 64, 128, idx); return; }
    idx -= (int)SZ_WXOUT;
    if (idx < (int)SZ_WHOUT) { ws[OFF_WHOUT + idx] = wh_midT(wh_out, 32, idx); return; }
    idx -= (int)SZ_WHOUT;
    if (idx < 256) { int f = idx >> 2, g = idx & 3; ws[OFF_BIN + idx] = b_in[g * 64 + f]; return; }
    idx -= 256;
    if (idx < 256) { int f = idx >> 2, g = idx & 3; ws[OFF_BR0 + idx] = b_r0[g * 64 + f]; return; }
    idx -= 256;
    if (idx < 256) { int f = idx >> 2, g = idx & 3; ws[OFF_BR1 + idx] = b_r1[g * 64 + f]; return; }
    idx -= 256;
    if (idx < 128) { int f = idx >> 2, g = idx & 3; ws[OFF_BOUT + idx] = b_out[g * 32 + f]; return; }
}

// ---------------------------------------------------------------------------
// build_features: gather [y | h | err | no] -> z0 f32 [28][1536][304]
// ---------------------------------------------------------------------------
__global__ __launch_bounds__(256)
void build_features_kernel(const float* __restrict__ y,
                           const float* __restrict__ h,
                           const float* __restrict__ ev,
                           const float* __restrict__ no,
                           float* __restrict__ z0)
{
    long long idx = (long long)blockIdx.x * 256 + threadIdx.x;
    const long long total = (long long)BB * TT * LL * CINP;
    if (idx >= total) return;
    int c = (int)(idx % CINP);
    long long rest = idx / CINP;
    int l = (int)(rest % LL); rest /= LL;
    int t = (int)(rest % TT);
    int b = (int)(rest / TT);
    float v = 0.0f;
    if (c < 32) {
        int na = c >> 1, ri = c & 1;
        v = y[((((long long)b * 16 + na) * TT + t) * LL + l) * 2 + ri];
    } else if (c < 288) {
        int q = c - 32;
        int ri = q & 1, nspu = (q >> 1) & 1, nue = (q >> 2) & 3, na = q >> 4;
        v = h[((((((long long)b * 16 + na) * 4 + nue) * 2 + nspu) * TT + t) * LL + l) * 2 + ri];
    } else if (c < 296) {
        int q = c - 288; int nspu = q & 1, nue = q >> 1;
        v = ev[(((long long)(nue * 2 + nspu) * TT + t) * LL) + l];
    } else if (c == 296) {
        v = no[0];
    }
    z0[idx] = v;
}

// ---------------------------------------------------------------------------
// xz_gemm (unchanged from R6/R7)
// ---------------------------------------------------------------------------
__device__ __forceinline__ int wsw(int n) { return n + ((n >> 5) << 2); }

__global__ __launch_bounds__(256)
void xz_gemm_kernel(const float* __restrict__ A, int CinPitch,
                    const float* __restrict__ Wg, const float* __restrict__ bias,
                    float* __restrict__ out, int Ncol)
{
    __shared__ float As[16 * 136];
    __shared__ float Ws[3 * 16 * 144];
    const int tid = threadIdx.x;
    const int bt = blockIdx.y;
    const int l0 = blockIdx.x * 128;
    const int n0 = blockIdx.z * 128;
    const int mbase = (tid >> 4) * 8;
    const int nbase = (tid & 15) * 8;
    const int nsw0 = wsw(nbase);
    const int nsw1 = wsw(nbase + 4);

    float acc[8][8];
#pragma unroll
    for (int i = 0; i < 8; i++)
#pragma unroll
        for (int j = 0; j < 8; j++) acc[i][j] = 0.0f;

    for (int cc0 = 0; cc0 < CinPitch; cc0 += 16) {
        __syncthreads();
        for (int idx = tid; idx < 130 * 16; idx += 256) {
            int r = idx >> 4, c = idx & 15;
            int row = l0 + r - 1;
            float v = 0.0f;
            if (row >= 0 && row < LL)
                v = A[((size_t)bt * LL + row) * CinPitch + cc0 + c];
            As[c * 136 + r] = v;
        }
        for (int i4 = tid; i4 < 3 * 16 * 32; i4 += 256) {
            int kh = i4 >> 9;
            int r2 = i4 & 511;
            int kk = r2 >> 5, n4 = r2 & 31;
            float4 w = *reinterpret_cast<const float4*>(
                &Wg[((size_t)kh * CinPitch + cc0 + kk) * Ncol + n0 + n4 * 4]);
            *reinterpret_cast<float4*>(&Ws[(kh * 16 + kk) * 144 + wsw(n4 * 4)]) = w;
        }
        __syncthreads();
        for (int kk = 0; kk < 16; ++kk) {
            float a[10];
            *reinterpret_cast<float4*>(&a[0]) =
                *reinterpret_cast<const float4*>(&As[kk * 136 + mbase]);
            *reinterpret_cast<float4*>(&a[4]) =
                *reinterpret_cast<const float4*>(&As[kk * 136 + mbase + 4]);
            *reinterpret_cast<float2*>(&a[8]) =
                *reinterpret_cast<const float2*>(&As[kk * 136 + mbase + 8]);
#pragma unroll
            for (int kh = 0; kh < 3; ++kh) {
                const float* wrow = &Ws[(kh * 16 + kk) * 144];
                float w[8];
                *reinterpret_cast<float4*>(&w[0]) =
                    *reinterpret_cast<const float4*>(&wrow[nsw0]);
                *reinterpret_cast<float4*>(&w[4]) =
                    *reinterpret_cast<const float4*>(&wrow[nsw1]);
#pragma unroll
                for (int i = 0; i < 8; i++)
#pragma unroll
                    for (int j = 0; j < 8; j++)
                        acc[i][j] = fmaf(a[i + kh], w[j], acc[i][j]);
            }
        }
    }
#pragma unroll
    for (int i = 0; i < 8; i++) {
        int row = l0 + mbase + i;
        float* orow = out + ((size_t)bt * LL + row) * Ncol + n0 + nbase;
        float4 o0, o1;
        o0.x = acc[i][0] + bias[n0 + nbase + 0];
        o0.y = acc[i][1] + bias[n0 + nbase + 1];
        o0.z = acc[i][2] + bias[n0 + nbase + 2];
        o0.w = acc[i][3] + bias[n0 + nbase + 3];
        o1.x = acc[i][4] + bias[n0 + nbase + 4];
        o1.y = acc[i][5] + bias[n0 + nbase + 5];
        o1.z = acc[i][6] + bias[n0 + nbase + 6];
        o1.w = acc[i][7] + bias[n0 + nbase + 7];
        *reinterpret_cast<float4*>(orow) = o0;
        *reinterpret_cast<float4*>(orow + 4) = o1;
    }
}

// ---------------------------------------------------------------------------
// lstm_scan: the WHOLE 14-step scan of one layer in one launch.
// Block = 16-row strip (192 blocks). Per step:
//   - halo rows of h_{t-1} come from neighbor blocks via device-scope atomic
//     edge buffer (parity double-buffered); interior h is in LDS (ping-pong);
//     c lives in registers (fixed (row,f) -> thread ownership across steps).
//   - spin-acquire on neighbor flags (epoch = layer*TT + t), release-publish
//     own flag after edge stores drain (syncthreads = per-wave vmcnt(0)).
// Max neighbor skew is 1 step -> 2-parity edge buffer is race-free.
// 192 blocks << co-residency capacity -> no deadlock.
// ---------------------------------------------------------------------------
template <int F_, bool RESID, bool OUTW>
__global__ __launch_bounds__(256)
void lstm_scan_kernel(const float* __restrict__ xz,   // [28][1536][F_*4] gate-interleaved
                      const float4* __restrict__ Wh4, // [3][F_][F_] float4 (i,f,g,o)
                      float* seq,                     // layer in/out seq (or null)
                      float* __restrict__ dout,       // final output f32 (or null)
                      float* __restrict__ edge,       // [2][NBLK][2][64]
                      int* __restrict__ flags,        // [NBLK]
                      int layer)
{
    constexpr int ROWS = 16;
    constexpr int RG = 256 / F_;        // 4 (F=64) / 8 (F=32)
    constexpr int R = ROWS / RG;        // 4 / 2
    constexpr int HP = F_ + 4;
    __shared__ float Hs[2][(ROWS + 2) * HP];

    const int tid = threadIdx.x;
    const int f   = tid % F_;
    const int rg  = tid / F_;
    const int blk = blockIdx.x;
    const int b   = blk / NSTRIP;
    const int strip = blk % NSTRIP;
    const int l0  = strip * ROWS;
    const int rgR = rg * R;

    // zero both h buffers (h_{-1} = 0)
    for (int idx = tid; idx < (ROWS + 2) * HP; idx += 256) {
        Hs[0][idx] = 0.0f;
        Hs[1][idx] = 0.0f;
    }

    float c[R];
#pragma unroll
    for (int i = 0; i < R; i++) c[i] = 0.0f;

    int cur = 0;
    for (int t = 0; t < TT; ++t) {
        if (t > 0) {
            // wait for neighbors' step t-1, then pull halo rows
            const int target = layer * TT + t;
            if (tid == 0 && strip > 0) {
                while (__hip_atomic_load(&flags[blk - 1], __ATOMIC_ACQUIRE,
                                         __HIP_MEMORY_SCOPE_AGENT) < target)
                    __builtin_amdgcn_s_sleep(1);
            }
            if (tid == 1 && strip < NSTRIP - 1) {
                while (__hip_atomic_load(&flags[blk + 1], __ATOMIC_ACQUIRE,
                                         __HIP_MEMORY_SCOPE_AGENT) < target)
                    __builtin_amdgcn_s_sleep(1);
            }
            __syncthreads();
            const int par = (t - 1) & 1;
            if (tid < F_) {                     // left halo: neighbor's row 15
                float v = 0.0f;
                if (strip > 0)
                    v = __hip_atomic_load(
                        &edge[(((size_t)par * NBLK + (blk - 1)) * 2 + 1) * 64 + tid],
                        __ATOMIC_RELAXED, __HIP_MEMORY_SCOPE_AGENT);
                Hs[cur][0 * HP + tid] = v;
            } else if (tid < 2 * F_) {          // right halo: neighbor's row 0
                int ff = tid - F_;
                float v = 0.0f;
                if (strip < NSTRIP - 1)
                    v = __hip_atomic_load(
                        &edge[(((size_t)par * NBLK + (blk + 1)) * 2 + 0) * 64 + ff],
                        __ATOMIC_RELAXED, __HIP_MEMORY_SCOPE_AGENT);
                Hs[cur][(ROWS + 1) * HP + ff] = v;
            }
            __syncthreads();
        }

        float4 zh[R];
#pragma unroll
        for (int i = 0; i < R; i++) zh[i] = make_float4(0.f, 0.f, 0.f, 0.f);

        if (t > 0) {
#pragma unroll
            for (int k = 0; k < 3; k++) {
                const float4* __restrict__ wk = Wh4 + (size_t)k * F_ * F_;
                const float* __restrict__ hk = &Hs[cur][(rgR + k) * HP];
#pragma unroll 2
                for (int c4 = 0; c4 < F_; c4 += 4) {
                    const float4 w0 = wk[(c4 + 0) * F_ + f];
                    const float4 w1 = wk[(c4 + 1) * F_ + f];
                    const float4 w2 = wk[(c4 + 2) * F_ + f];
                    const float4 w3 = wk[(c4 + 3) * F_ + f];
#pragma unroll
                    for (int i = 0; i < R; i++) {
                        const float4 h4 = *reinterpret_cast<const float4*>(&hk[i * HP + c4]);
                        zh[i].x = fmaf(h4.x, w0.x, zh[i].x);
                        zh[i].y = fmaf(h4.x, w0.y, zh[i].y);
                        zh[i].z = fmaf(h4.x, w0.z, zh[i].z);
                        zh[i].w = fmaf(h4.x, w0.w, zh[i].w);
                        zh[i].x = fmaf(h4.y, w1.x, zh[i].x);
                        zh[i].y = fmaf(h4.y, w1.y, zh[i].y);
                        zh[i].z = fmaf(h4.y, w1.z, zh[i].z);
                        zh[i].w = fmaf(h4.y, w1.w, zh[i].w);
                        zh[i].x = fmaf(h4.z, w2.x, zh[i].x);
                        zh[i].y = fmaf(h4.z, w2.y, zh[i].y);
                        zh[i].z = fmaf(h4.z, w2.z, zh[i].z);
                        zh[i].w = fmaf(h4.z, w2.w, zh[i].w);
                        zh[i].x = fmaf(h4.w, w3.x, zh[i].x);
                        zh[i].y = fmaf(h4.w, w3.y, zh[i].y);
                        zh[i].z = fmaf(h4.w, w3.z, zh[i].z);
                        zh[i].w = fmaf(h4.w, w3.w, zh[i].w);
                    }
                }
            }
        }

        const size_t btL = ((size_t)b * TT + t) * LL;
        const int nxt = cur ^ 1;
        const int parw = t & 1;
#pragma unroll
        for (int i = 0; i < R; i++) {
            const int r = rgR + i;              // block-local row 0..15
            const int l = l0 + r;
            const float4 z4 = *reinterpret_cast<const float4*>(
                &xz[(btL + l) * (size_t)(4 * F_) + f * 4]);
            float zi = z4.x + zh[i].x;
            float zf = z4.y + zh[i].y;
            float zg = z4.z + zh[i].z;
            float zo = z4.w + zh[i].w;
            float ig = hsig(zi), fg = hsig(zf);
            float gg = tanhf(zg), og = hsig(zo);
            float cn = fg * c[i] + ig * gg;
            float hn = og * tanhf(cn);
            c[i] = cn;
            Hs[nxt][(1 + r) * HP + f] = hn;
            if (r == 0)
                __hip_atomic_store(
                    &edge[(((size_t)parw * NBLK + blk) * 2 + 0) * 64 + f], hn,
                    __ATOMIC_RELAXED, __HIP_MEMORY_SCOPE_AGENT);
            if (r == ROWS - 1)
                __hip_atomic_store(
                    &edge[(((size_t)parw * NBLK + blk) * 2 + 1) * 64 + f], hn,
                    __ATOMIC_RELAXED, __HIP_MEMORY_SCOPE_AGENT);
            if (OUTW) {
                // out[b][ue][spu][n*4+bit]; f = ue*8 + spu*4 + bit; n = t*L + l
                int ue = f >> 3, spu = (f >> 2) & 1, bit = f & 3;
                size_t n = (size_t)t * LL + l;
                dout[(((size_t)b * 4 + ue) * 2 + spu) * ((size_t)TT * LL * 4) + n * 4 + bit] = hn;
            } else {
                float v = hn;
                if (RESID) v += seq[(btL + l) * F_ + f];   // same idx, same thread
                seq[(btL + l) * F_ + f] = v;
            }
        }
        // all waves drain their global stores at this barrier (vmcnt(0)),
        // so the release below publishes completed edge data.
        __syncthreads();
        if (tid == 0)
            __hip_atomic_store(&flags[blk], layer * TT + t + 1,
                               __ATOMIC_RELEASE, __HIP_MEMORY_SCOPE_AGENT);
        cur = nxt;
    }
}

// ---------------------------------------------------------------------------
extern "C" void kernel_launch(void* const* d_in, const int* in_sizes, int n_in,
                              void* d_out, int out_size, void* d_ws, size_t ws_size,
                              hipStream_t stream)
{
    (void)in_sizes; (void)n_in; (void)out_size; (void)ws_size;
    const float* y_ri   = (const float*)d_in[0];
    const float* h_ri   = (const float*)d_in[1];
    const float* evar   = (const float*)d_in[2];
    const float* no     = (const float*)d_in[3];
    const float* wx_in  = (const float*)d_in[4];
    const float* wh_in  = (const float*)d_in[5];
    const float* b_in   = (const float*)d_in[6];
    const float* wx_r0  = (const float*)d_in[7];
    const float* wh_r0  = (const float*)d_in[8];
    const float* b_r0   = (const float*)d_in[9];
    const float* wx_r1  = (const float*)d_in[10];
    const float* wh_r1  = (const float*)d_in[11];
    const float* b_r1   = (const float*)d_in[12];
    const float* wx_out = (const float*)d_in[13];
    const float* wh_out = (const float*)d_in[14];
    const float* b_out  = (const float*)d_in[15];

    float* ws = (float*)d_ws;
    float* dout = (float*)d_out;

    {
        int blocks = (int)((PREP_TOTAL + 255) / 256);
        prep_weights_kernel<<<blocks, 256, 0, stream>>>(
            wx_in, wh_in, b_in, wx_r0, wh_r0, b_r0,
            wx_r1, wh_r1, b_r1, wx_out, wh_out, b_out, ws);
    }
    {
        long long total = (long long)BB * TT * LL * CINP;
        int blocks = (int)((total + 255) / 256);
        build_features_kernel<<<blocks, 256, 0, stream>>>(
            y_ri, h_ri, evar, no, ws + OFF_Z0);
    }
    // zero scan flags (graph-capturable memset node)
    hipMemsetAsync(ws + OFF_FLAGS, 0, NBLK * sizeof(int), stream);

    float* seq   = ws + OFF_SEQ;
    float* edge  = ws + OFF_EDGE;
    int*   flags = (int*)(ws + OFF_FLAGS);
    const dim3 g256(12, BB * TT, 2);
    const dim3 g128(12, BB * TT, 1);

    // ---- layer in: Cin=297(p304) -> F=64
    xz_gemm_kernel<<<g256, 256, 0, stream>>>(
        ws + OFF_Z0, CINP, ws + OFF_WXIN, ws + OFF_BIN, ws + OFF_XZ, 256);
    lstm_scan_kernel<64, false, false><<<NBLK, 256, 0, stream>>>(
        ws + OFF_XZ, (const float4*)(ws + OFF_WHIN), seq, nullptr, edge, flags, 0);

    // ---- layer r0 (+residual, in-place on seq)
    xz_gemm_kernel<<<g256, 256, 0, stream>>>(
        seq, 64, ws + OFF_WXR0, ws + OFF_BR0, ws + OFF_XZ, 256);
    lstm_scan_kernel<64, true, false><<<NBLK, 256, 0, stream>>>(
        ws + OFF_XZ, (const float4*)(ws + OFF_WHR0), seq, nullptr, edge, flags, 1);

    // ---- layer r1 (+residual, in-place on seq)
    xz_gemm_kernel<<<g256, 256, 0, stream>>>(
        seq, 64, ws + OFF_WXR1, ws + OFF_BR1, ws + OFF_XZ, 256);
    lstm_scan_kernel<64, true, false><<<NBLK, 256, 0, stream>>>(
        ws + OFF_XZ, (const float4*)(ws + OFF_WHR1), seq, nullptr, edge, flags, 2);

    // ---- layer out: F=32, writes d_out (f32, transposed layout)
    xz_gemm_kernel<<<g128, 256, 0, stream>>>(
        seq, 64, ws + OFF_WXOUT, ws + OFF_BOUT, ws + OFF_XZ, 128);
    lstm_scan_kernel<32, false, true><<<NBLK, 256, 0, stream>>>(
        ws + OFF_XZ, (const float4*)(ws + OFF_WHOUT), nullptr, dout, edge, flags, 3);
}

// Round 9
// 1170.413 us; speedup vs baseline: 1.2059x; 1.2059x over previous
//
#include <hip/hip_runtime.h>
#include <hip/hip_bf16.h>

// ---------------------------------------------------------------------------
// PUSCH neural detector: 4 stacked ConvLSTM layers on [B=2,T=14,H=1536,W=1].
// 3x3 conv degenerates to width-3 conv along H (kw=1 slice).
// Round 9: MFMA scan — Wh as bf16 B-fragments resident in registers for the
// whole 14-step scan (kills the per-step per-wave 192KB weight re-stream that
// R5-R8 counters showed to be the intrinsic ~15us/step cost). h recurrence in
// bf16 via LDS; c/seq/xz stay f32. Strip/edge/flag sync scheme from R8.
// ---------------------------------------------------------------------------

#define BB   2
#define TT   14
#define LL   1536
#define CINR 297
#define CINP 304
#define NSTRIP 96                 // LL / 16
#define NBLK  (BB * NSTRIP)       // 192 scan blocks

typedef __attribute__((ext_vector_type(8))) short short8;   // 8 bf16 = 4 VGPRs
typedef __attribute__((ext_vector_type(4))) float floatx4;  // MFMA C/D

// ---- workspace layout (units: f32 elements) -------------------------------
static constexpr size_t SZ_WXIN  = (size_t)3*CINP*256;   // 233472
static constexpr size_t SZ_WX64  = (size_t)3*64*256;     // 49152
static constexpr size_t SZ_WXOUT = (size_t)3*64*128;     // 24576

static constexpr size_t OFF_WXIN  = 0;
static constexpr size_t OFF_WXR0  = OFF_WXIN  + SZ_WXIN;   // 233472
static constexpr size_t OFF_WXR1  = OFF_WXR0  + SZ_WX64;   // 282624
static constexpr size_t OFF_WXOUT = OFF_WXR1  + SZ_WX64;   // 331776
static constexpr size_t OFF_BIN   = OFF_WXOUT + SZ_WXOUT;  // 356352
static constexpr size_t OFF_BR0   = OFF_BIN + 256;
static constexpr size_t OFF_BR1   = OFF_BR0 + 256;
static constexpr size_t OFF_BOUT  = OFF_BR1 + 256;
static constexpr size_t P_F32TOT  = OFF_BOUT + 128;        // 357248
// bf16 WhT arrays (u16 elements), [n][k] gate-plane transposed
static constexpr size_t U_WHTIN  = 49152;   // [256][192]
static constexpr size_t U_WHTOUT = 12288;   // [128][96]
static constexpr size_t OFF_WHTIN  = P_F32TOT;                  // u16 region
static constexpr size_t OFF_WHTR0  = OFF_WHTIN  + U_WHTIN/2;
static constexpr size_t OFF_WHTR1  = OFF_WHTR0  + U_WHTIN/2;
static constexpr size_t OFF_WHTOUT = OFF_WHTR1  + U_WHTIN/2;
static constexpr size_t PREP_TOTAL = P_F32TOT + 3*U_WHTIN + U_WHTOUT; // threads

static constexpr size_t OFF_Z0  = 524288;                 // f32 [28][1536][304]
static constexpr size_t SZ_Z0   = (size_t)BB*TT*LL*CINP;
static constexpr size_t OFF_XZ  = OFF_Z0 + SZ_Z0;         // f32 [28][1536][256]
static constexpr size_t SZ_XZ   = (size_t)BB*TT*LL*256;
static constexpr size_t OFF_SEQ = OFF_XZ + SZ_XZ;         // f32 [28][1536][64]
static constexpr size_t SZ_SEQ  = (size_t)BB*TT*LL*64;
static constexpr size_t OFF_EDGE = OFF_SEQ + SZ_SEQ;      // f32 [2][NBLK][2][64]
static constexpr size_t SZ_EDGE  = (size_t)2*NBLK*2*64;
static constexpr size_t OFF_FLAGS = OFF_EDGE + SZ_EDGE;   // NBLK ints
// ~110 MB total

__device__ __forceinline__ float hsig(float x) {
    return fminf(fmaxf(0.2f * x + 0.5f, 0.0f), 1.0f);
}
__device__ __forceinline__ unsigned short f2bf(float x) {
    unsigned int u = __builtin_bit_cast(unsigned int, x);
    u += 0x7fffu + ((u >> 16) & 1u);          // round-to-nearest-even
    return (unsigned short)(u >> 16);
}

// ---------------------------------------------------------------------------
// prep_weights.
// Wx stored [k][ci][co'] with co' = f*4+g (gate-interleaved -> epilogue float4)
// WhT stored bf16 [n][k], n = g*F+f (gate-plane), k = kh*F+ci (MFMA B-frags).
// Biases permuted to co'.
// ---------------------------------------------------------------------------
__device__ __forceinline__ float wx_midP(const float* src, int Cin, int N, int idx) {
    int k = idx / (Cin * N); int r = idx - k * (Cin * N);
    int ci = r / N; int cop = r - ci * N;
    int Fo = N >> 2;
    int f = cop >> 2, g = cop & 3;
    return src[((size_t)(k * 3 + 1) * Cin + ci) * N + g * Fo + f];
}

__global__ __launch_bounds__(256)
void prep_weights_kernel(const float* wx_in, const float* wh_in, const float* b_in,
                         const float* wx_r0, const float* wh_r0, const float* b_r0,
                         const float* wx_r1, const float* wh_r1, const float* b_r1,
                         const float* wx_out, const float* wh_out, const float* b_out,
                         float* __restrict__ ws)
{
    int idx = blockIdx.x * 256 + threadIdx.x;
    if (idx < (int)SZ_WXIN) {
        int k = idx / (CINP * 256); int r = idx - k * (CINP * 256);
        int ci = r >> 8; int cop = r & 255;
        float v = 0.0f;
        if (ci < CINR) {
            int f = cop >> 2, g = cop & 3;
            v = wx_in[((size_t)(k * 3 + 1) * CINR + ci) * 256 + g * 64 + f];
        }
        ws[OFF_WXIN + idx] = v; return;
    }
    idx -= (int)SZ_WXIN;
    if (idx < (int)SZ_WX64) { ws[OFF_WXR0 + idx] = wx_midP(wx_r0, 64, 256, idx); return; }
    idx -= (int)SZ_WX64;
    if (idx < (int)SZ_WX64) { ws[OFF_WXR1 + idx] = wx_midP(wx_r1, 64, 256, idx); return; }
    idx -= (int)SZ_WX64;
    if (idx < (int)SZ_WXOUT) { ws[OFF_WXOUT + idx] = wx_midP(wx_out, 64, 128, idx); return; }
    idx -= (int)SZ_WXOUT;
    if (idx < 256) { int f = idx >> 2, g = idx & 3; ws[OFF_BIN + idx] = b_in[g * 64 + f]; return; }
    idx -= 256;
    if (idx < 256) { int f = idx >> 2, g = idx & 3; ws[OFF_BR0 + idx] = b_r0[g * 64 + f]; return; }
    idx -= 256;
    if (idx < 256) { int f = idx >> 2, g = idx & 3; ws[OFF_BR1 + idx] = b_r1[g * 64 + f]; return; }
    idx -= 256;
    if (idx < 128) { int f = idx >> 2, g = idx & 3; ws[OFF_BOUT + idx] = b_out[g * 32 + f]; return; }
    idx -= 128;
    // ---- bf16 WhT sections (u16 writes) ----
    if (idx < (int)U_WHTIN) {
        int n = idx / 192, k = idx % 192, kh = k >> 6, ci = k & 63;
        ((unsigned short*)(ws + OFF_WHTIN))[idx] =
            f2bf(wh_in[((size_t)(kh * 3 + 1) * 64 + ci) * 256 + n]);
        return;
    }
    idx -= (int)U_WHTIN;
    if (idx < (int)U_WHTIN) {
        int n = idx / 192, k = idx % 192, kh = k >> 6, ci = k & 63;
        ((unsigned short*)(ws + OFF_WHTR0))[idx] =
            f2bf(wh_r0[((size_t)(kh * 3 + 1) * 64 + ci) * 256 + n]);
        return;
    }
    idx -= (int)U_WHTIN;
    if (idx < (int)U_WHTIN) {
        int n = idx / 192, k = idx % 192, kh = k >> 6, ci = k & 63;
        ((unsigned short*)(ws + OFF_WHTR1))[idx] =
            f2bf(wh_r1[((size_t)(kh * 3 + 1) * 64 + ci) * 256 + n]);
        return;
    }
    idx -= (int)U_WHTIN;
    if (idx < (int)U_WHTOUT) {
        int n = idx / 96, k = idx % 96, kh = k / 32, ci = k % 32;
        ((unsigned short*)(ws + OFF_WHTOUT))[idx] =
            f2bf(wh_out[((size_t)(kh * 3 + 1) * 32 + ci) * 128 + n]);
        return;
    }
}

// ---------------------------------------------------------------------------
// build_features: gather [y | h | err | no] -> z0 f32 [28][1536][304]
// ---------------------------------------------------------------------------
__global__ __launch_bounds__(256)
void build_features_kernel(const float* __restrict__ y,
                           const float* __restrict__ h,
                           const float* __restrict__ ev,
                           const float* __restrict__ no,
                           float* __restrict__ z0)
{
    long long idx = (long long)blockIdx.x * 256 + threadIdx.x;
    const long long total = (long long)BB * TT * LL * CINP;
    if (idx >= total) return;
    int c = (int)(idx % CINP);
    long long rest = idx / CINP;
    int l = (int)(rest % LL); rest /= LL;
    int t = (int)(rest % TT);
    int b = (int)(rest / TT);
    float v = 0.0f;
    if (c < 32) {
        int na = c >> 1, ri = c & 1;
        v = y[((((long long)b * 16 + na) * TT + t) * LL + l) * 2 + ri];
    } else if (c < 288) {
        int q = c - 32;
        int ri = q & 1, nspu = (q >> 1) & 1, nue = (q >> 2) & 3, na = q >> 4;
        v = h[((((((long long)b * 16 + na) * 4 + nue) * 2 + nspu) * TT + t) * LL + l) * 2 + ri];
    } else if (c < 296) {
        int q = c - 288; int nspu = q & 1, nue = q >> 1;
        v = ev[(((long long)(nue * 2 + nspu) * TT + t) * LL) + l];
    } else if (c == 296) {
        v = no[0];
    }
    z0[idx] = v;
}

// ---------------------------------------------------------------------------
// xz_gemm (unchanged from R6-R8)
// ---------------------------------------------------------------------------
__device__ __forceinline__ int wsw(int n) { return n + ((n >> 5) << 2); }

__global__ __launch_bounds__(256)
void xz_gemm_kernel(const float* __restrict__ A, int CinPitch,
                    const float* __restrict__ Wg, const float* __restrict__ bias,
                    float* __restrict__ out, int Ncol)
{
    __shared__ float As[16 * 136];
    __shared__ float Ws[3 * 16 * 144];
    const int tid = threadIdx.x;
    const int bt = blockIdx.y;
    const int l0 = blockIdx.x * 128;
    const int n0 = blockIdx.z * 128;
    const int mbase = (tid >> 4) * 8;
    const int nbase = (tid & 15) * 8;
    const int nsw0 = wsw(nbase);
    const int nsw1 = wsw(nbase + 4);

    float acc[8][8];
#pragma unroll
    for (int i = 0; i < 8; i++)
#pragma unroll
        for (int j = 0; j < 8; j++) acc[i][j] = 0.0f;

    for (int cc0 = 0; cc0 < CinPitch; cc0 += 16) {
        __syncthreads();
        for (int idx = tid; idx < 130 * 16; idx += 256) {
            int r = idx >> 4, c = idx & 15;
            int row = l0 + r - 1;
            float v = 0.0f;
            if (row >= 0 && row < LL)
                v = A[((size_t)bt * LL + row) * CinPitch + cc0 + c];
            As[c * 136 + r] = v;
        }
        for (int i4 = tid; i4 < 3 * 16 * 32; i4 += 256) {
            int kh = i4 >> 9;
            int r2 = i4 & 511;
            int kk = r2 >> 5, n4 = r2 & 31;
            float4 w = *reinterpret_cast<const float4*>(
                &Wg[((size_t)kh * CinPitch + cc0 + kk) * Ncol + n0 + n4 * 4]);
            *reinterpret_cast<float4*>(&Ws[(kh * 16 + kk) * 144 + wsw(n4 * 4)]) = w;
        }
        __syncthreads();
        for (int kk = 0; kk < 16; ++kk) {
            float a[10];
            *reinterpret_cast<float4*>(&a[0]) =
                *reinterpret_cast<const float4*>(&As[kk * 136 + mbase]);
            *reinterpret_cast<float4*>(&a[4]) =
                *reinterpret_cast<const float4*>(&As[kk * 136 + mbase + 4]);
            *reinterpret_cast<float2*>(&a[8]) =
                *reinterpret_cast<const float2*>(&As[kk * 136 + mbase + 8]);
#pragma unroll
            for (int kh = 0; kh < 3; ++kh) {
                const float* wrow = &Ws[(kh * 16 + kk) * 144];
                float w[8];
                *reinterpret_cast<float4*>(&w[0]) =
                    *reinterpret_cast<const float4*>(&wrow[nsw0]);
                *reinterpret_cast<float4*>(&w[4]) =
                    *reinterpret_cast<const float4*>(&wrow[nsw1]);
#pragma unroll
                for (int i = 0; i < 8; i++)
#pragma unroll
                    for (int j = 0; j < 8; j++)
                        acc[i][j] = fmaf(a[i + kh], w[j], acc[i][j]);
            }
        }
    }
#pragma unroll
    for (int i = 0; i < 8; i++) {
        int row = l0 + mbase + i;
        float* orow = out + ((size_t)bt * LL + row) * Ncol + n0 + nbase;
        float4 o0, o1;
        o0.x = acc[i][0] + bias[n0 + nbase + 0];
        o0.y = acc[i][1] + bias[n0 + nbase + 1];
        o0.z = acc[i][2] + bias[n0 + nbase + 2];
        o0.w = acc[i][3] + bias[n0 + nbase + 3];
        o1.x = acc[i][4] + bias[n0 + nbase + 4];
        o1.y = acc[i][5] + bias[n0 + nbase + 5];
        o1.z = acc[i][6] + bias[n0 + nbase + 6];
        o1.w = acc[i][7] + bias[n0 + nbase + 7];
        *reinterpret_cast<float4*>(orow) = o0;
        *reinterpret_cast<float4*>(orow + 4) = o1;
    }
}

// ---------------------------------------------------------------------------
// lstm_scan (MFMA): 14 steps in one launch. Block = 16-row strip, NW=F/16
// waves; wave w owns f-range [16w,16w+16) for all 4 gates. B-fragments
// (bf16 WhT) loaded ONCE into registers (4 gates x KS k-steps x 4 VGPRs).
// Per step: 6 (or 3) ds_read_b128 A-frags from bf16 h in LDS + 24 (or 12)
// v_mfma_f32_16x16x32_bf16 + lane-local gate epilogue (C-layout: row=
// quad*4+reg, col=lane&15 -> all 4 gates of one (row,f) in the same lane).
// c in registers; edges f32 via device-scope atomics + flag acquire/release
// (scheme verified in R8). h halo converted to bf16 on LDS fill.
// ---------------------------------------------------------------------------
template <int F_, bool RESID, bool OUTW>
__global__ __launch_bounds__(64 * (F_ / 16))
void lstm_scan_kernel(const float* __restrict__ xz,           // [28][1536][4F] co'=f*4+g
                      const unsigned short* __restrict__ WhT, // [4F][3F] bf16
                      float* seq,                             // layer in/out (or null)
                      float* __restrict__ dout,               // final out (or null)
                      float* __restrict__ edge,               // [2][NBLK][2][64] f32
                      int* __restrict__ flags,                // [NBLK]
                      int layer)
{
    constexpr int NW = F_ / 16;
    constexpr int NT = 64 * NW;
    constexpr int K  = 3 * F_;
    constexpr int KS = K / 32;          // 6 (F=64) / 3 (F=32)
    constexpr int KH = KS / 3;          // k-steps per conv tap: 2 / 1
    constexpr int HP = F_ + 8;          // u16 pitch (2-way-free bank rotation)
    __shared__ unsigned short Hs[2][18 * HP];

    const int tid  = threadIdx.x;
    const int lane = tid & 63;
    const int wv   = tid >> 6;
    const int m    = lane & 15;         // A row / C col index
    const int quad = lane >> 4;
    const int fw0  = wv * 16;
    const int blk  = blockIdx.x;
    const int b    = blk / NSTRIP;
    const int strip = blk % NSTRIP;
    const int l0   = strip * 16;
    const int f    = fw0 + m;           // this lane's f

    // ---- B-fragments, resident for the whole scan ----
    short8 bf[4][KS];
#pragma unroll
    for (int g = 0; g < 4; g++)
#pragma unroll
        for (int ks = 0; ks < KS; ks++) {
            const int n  = g * F_ + fw0 + m;
            const int k0 = ks * 32 + quad * 8;
            bf[g][ks] = *reinterpret_cast<const short8*>(&WhT[(size_t)n * K + k0]);
        }

    for (int idx = tid; idx < 18 * HP; idx += NT) { Hs[0][idx] = 0; Hs[1][idx] = 0; }
    __syncthreads();

    float c[4] = {0.f, 0.f, 0.f, 0.f};
    int cur = 0;
    for (int t = 0; t < TT; ++t) {
        floatx4 zi = {0.f, 0.f, 0.f, 0.f};
        floatx4 zf = {0.f, 0.f, 0.f, 0.f};
        floatx4 zg = {0.f, 0.f, 0.f, 0.f};
        floatx4 zo = {0.f, 0.f, 0.f, 0.f};

        if (t > 0) {
            const int target = layer * TT + t;
            if (tid == 0 && strip > 0) {
                while (__hip_atomic_load(&flags[blk - 1], __ATOMIC_ACQUIRE,
                                         __HIP_MEMORY_SCOPE_AGENT) < target)
                    __builtin_amdgcn_s_sleep(1);
            }
            if (tid == 1 && strip < NSTRIP - 1) {
                while (__hip_atomic_load(&flags[blk + 1], __ATOMIC_ACQUIRE,
                                         __HIP_MEMORY_SCOPE_AGENT) < target)
                    __builtin_amdgcn_s_sleep(1);
            }
            __syncthreads();
            const int par = (t - 1) & 1;
            if (tid < F_) {                     // left halo: neighbor's row 15
                float v = 0.0f;
                if (strip > 0)
                    v = __hip_atomic_load(
                        &edge[(((size_t)par * NBLK + (blk - 1)) * 2 + 1) * 64 + tid],
                        __ATOMIC_RELAXED, __HIP_MEMORY_SCOPE_AGENT);
                Hs[cur][0 * HP + tid] = f2bf(v);
            } else if (tid < 2 * F_) {          // right halo: neighbor's row 0
                int ff = tid - F_;
                float v = 0.0f;
                if (strip < NSTRIP - 1)
                    v = __hip_atomic_load(
                        &edge[(((size_t)par * NBLK + (blk + 1)) * 2 + 0) * 64 + ff],
                        __ATOMIC_RELAXED, __HIP_MEMORY_SCOPE_AGENT);
                Hs[cur][17 * HP + ff] = f2bf(v);
            }
            __syncthreads();

            // K-loop: conv taps x ci-halves, all MFMA
#pragma unroll
            for (int kh = 0; kh < 3; kh++) {
#pragma unroll
                for (int hf = 0; hf < KH; hf++) {
                    const short8 af = *reinterpret_cast<const short8*>(
                        &Hs[cur][(m + kh) * HP + hf * 32 + quad * 8]);
                    const int ks = kh * KH + hf;
                    zi = __builtin_amdgcn_mfma_f32_16x16x32_bf16(af, bf[0][ks], zi, 0, 0, 0);
                    zf = __builtin_amdgcn_mfma_f32_16x16x32_bf16(af, bf[1][ks], zf, 0, 0, 0);
                    zg = __builtin_amdgcn_mfma_f32_16x16x32_bf16(af, bf[2][ks], zg, 0, 0, 0);
                    zo = __builtin_amdgcn_mfma_f32_16x16x32_bf16(af, bf[3][ks], zo, 0, 0, 0);
                }
            }
        }

        // ---- epilogue: gates, state update, h publish ----
        const size_t btL = ((size_t)b * TT + t) * LL;
        const int nxt = cur ^ 1;
        const int parw = t & 1;
#pragma unroll
        for (int reg = 0; reg < 4; reg++) {
            const int r = quad * 4 + reg;       // block-local row 0..15
            const int l = l0 + r;
            const float4 z4 = *reinterpret_cast<const float4*>(
                &xz[(btL + l) * (size_t)(4 * F_) + f * 4]);
            const float vzi = z4.x + zi[reg];
            const float vzf = z4.y + zf[reg];
            const float vzg = z4.z + zg[reg];
            const float vzo = z4.w + zo[reg];
            const float ig = hsig(vzi), fg = hsig(vzf);
            const float gg = tanhf(vzg), og = hsig(vzo);
            const float cn = fg * c[reg] + ig * gg;
            const float hn = og * tanhf(cn);
            c[reg] = cn;
            Hs[nxt][(1 + r) * HP + f] = f2bf(hn);
            if (r == 0)
                __hip_atomic_store(
                    &edge[(((size_t)parw * NBLK + blk) * 2 + 0) * 64 + f], hn,
                    __ATOMIC_RELAXED, __HIP_MEMORY_SCOPE_AGENT);
            if (r == 15)
                __hip_atomic_store(
                    &edge[(((size_t)parw * NBLK + blk) * 2 + 1) * 64 + f], hn,
                    __ATOMIC_RELAXED, __HIP_MEMORY_SCOPE_AGENT);
            if (OUTW) {
                // out[b][ue][spu][n*4+bit]; f = ue*8+spu*4+bit; n = t*L+l
                const int ue = f >> 3, spu = (f >> 2) & 1, bit = f & 3;
                const size_t n = (size_t)t * LL + l;
                dout[(((size_t)b * 4 + ue) * 2 + spu) * ((size_t)TT * LL * 4) + n * 4 + bit] = hn;
            } else {
                float v = hn;
                if (RESID) v += seq[(btL + l) * F_ + f];   // same idx, same thread
                seq[(btL + l) * F_ + f] = v;
            }
        }
        __syncthreads();      // drains LDS + global stores before publication
        if (tid == 0)
            __hip_atomic_store(&flags[blk], layer * TT + t + 1,
                               __ATOMIC_RELEASE, __HIP_MEMORY_SCOPE_AGENT);
        cur = nxt;
    }
}

// ---------------------------------------------------------------------------
extern "C" void kernel_launch(void* const* d_in, const int* in_sizes, int n_in,
                              void* d_out, int out_size, void* d_ws, size_t ws_size,
                              hipStream_t stream)
{
    (void)in_sizes; (void)n_in; (void)out_size; (void)ws_size;
    const float* y_ri   = (const float*)d_in[0];
    const float* h_ri   = (const float*)d_in[1];
    const float* evar   = (const float*)d_in[2];
    const float* no     = (const float*)d_in[3];
    const float* wx_in  = (const float*)d_in[4];
    const float* wh_in  = (const float*)d_in[5];
    const float* b_in   = (const float*)d_in[6];
    const float* wx_r0  = (const float*)d_in[7];
    const float* wh_r0  = (const float*)d_in[8];
    const float* b_r0   = (const float*)d_in[9];
    const float* wx_r1  = (const float*)d_in[10];
    const float* wh_r1  = (const float*)d_in[11];
    const float* b_r1   = (const float*)d_in[12];
    const float* wx_out = (const float*)d_in[13];
    const float* wh_out = (const float*)d_in[14];
    const float* b_out  = (const float*)d_in[15];

    float* ws = (float*)d_ws;
    float* dout = (float*)d_out;

    {
        int blocks = (int)((PREP_TOTAL + 255) / 256);
        prep_weights_kernel<<<blocks, 256, 0, stream>>>(
            wx_in, wh_in, b_in, wx_r0, wh_r0, b_r0,
            wx_r1, wh_r1, b_r1, wx_out, wh_out, b_out, ws);
    }
    {
        long long total = (long long)BB * TT * LL * CINP;
        int blocks = (int)((total + 255) / 256);
        build_features_kernel<<<blocks, 256, 0, stream>>>(
            y_ri, h_ri, evar, no, ws + OFF_Z0);
    }
    hipMemsetAsync(ws + OFF_FLAGS, 0, NBLK * sizeof(int), stream);

    float* seq   = ws + OFF_SEQ;
    float* edge  = ws + OFF_EDGE;
    int*   flags = (int*)(ws + OFF_FLAGS);
    const dim3 g256(12, BB * TT, 2);
    const dim3 g128(12, BB * TT, 1);

    // ---- layer in: Cin=297(p304) -> F=64
    xz_gemm_kernel<<<g256, 256, 0, stream>>>(
        ws + OFF_Z0, CINP, ws + OFF_WXIN, ws + OFF_BIN, ws + OFF_XZ, 256);
    lstm_scan_kernel<64, false, false><<<NBLK, 256, 0, stream>>>(
        ws + OFF_XZ, (const unsigned short*)(ws + OFF_WHTIN),
        seq, nullptr, edge, flags, 0);

    // ---- layer r0 (+residual, in-place on seq)
    xz_gemm_kernel<<<g256, 256, 0, stream>>>(
        seq, 64, ws + OFF_WXR0, ws + OFF_BR0, ws + OFF_XZ, 256);
    lstm_scan_kernel<64, true, false><<<NBLK, 256, 0, stream>>>(
        ws + OFF_XZ, (const unsigned short*)(ws + OFF_WHTR0),
        seq, nullptr, edge, flags, 1);

    // ---- layer r1 (+residual, in-place on seq)
    xz_gemm_kernel<<<g256, 256, 0, stream>>>(
        seq, 64, ws + OFF_WXR1, ws + OFF_BR1, ws + OFF_XZ, 256);
    lstm_scan_kernel<64, true, false><<<NBLK, 256, 0, stream>>>(
        ws + OFF_XZ, (const unsigned short*)(ws + OFF_WHTR1),
        seq, nullptr, edge, flags, 2);

    // ---- layer out: F=32, writes d_out (f32, transposed layout)
    xz_gemm_kernel<<<g128, 256, 0, stream>>>(
        seq, 64, ws + OFF_WXOUT, ws + OFF_BOUT, ws + OFF_XZ, 128);
    lstm_scan_kernel<32, false, true><<<NBLK, 128, 0, stream>>>(
        ws + OFF_XZ, (const unsigned short*)(ws + OFF_WHTOUT),
        nullptr, dout, edge, flags, 3);
}

// Round 10
// 962.068 us; speedup vs baseline: 1.4671x; 1.2166x over previous
//
#include <hip/hip_runtime.h>
#include <hip/hip_bf16.h>

// ---------------------------------------------------------------------------
// PUSCH neural detector: 4 stacked ConvLSTM layers on [B=2,T=14,H=1536,W=1].
// 3x3 conv degenerates to width-3 conv along H (kw=1 slice).
// Round 10: MFMA conv-GEMMs with hi/lo bf16 split (f32-grade accuracy, matrix
// pipe instead of f32 VALU). Scans unchanged from R9 (MFMA, register-resident
// weights) except they additionally emit bf16 hi/lo planes of seq for the
// next layer's GEMM. Workspace re-planned: seq aliases the dead z0 region.
// ---------------------------------------------------------------------------

#define BB   2
#define TT   14
#define LL   1536
#define CINR 297
#define CP_IN 320                 // padded input channels (10 chunks of 32)
#define NSTRIP 96                 // LL / 16
#define NBLK  (BB * NSTRIP)       // 192 scan blocks

typedef __attribute__((ext_vector_type(8))) short short8;   // 8 bf16 = 4 VGPRs
typedef __attribute__((ext_vector_type(4))) float floatx4;  // MFMA C/D

// ---- workspace layout -----------------------------------------------------
// u16 offsets (from (ushort*)ws) for weight planes:
static constexpr size_t U_WBIN_HI  = 0;         // [256][960]
static constexpr size_t U_WBIN_LO  = 245760;
static constexpr size_t U_WBR0_HI  = 491520;    // [256][192]
static constexpr size_t U_WBR0_LO  = 540672;
static constexpr size_t U_WBR1_HI  = 589824;
static constexpr size_t U_WBR1_LO  = 638976;
static constexpr size_t U_WBOUT_HI = 688128;    // [128][192]
static constexpr size_t U_WBOUT_LO = 712704;
static constexpr size_t U_WHTIN    = 737280;    // [256][192] scan WhT bf16
static constexpr size_t U_WHTR0    = 786432;
static constexpr size_t U_WHTR1    = 835584;
static constexpr size_t U_WHTOUT   = 884736;    // [128][96]
// f32 offsets:
static constexpr size_t OFF_BIN   = 448512;     // gate-interleaved biases
static constexpr size_t OFF_BR0   = 448768;
static constexpr size_t OFF_BR1   = 449024;
static constexpr size_t OFF_BOUT  = 449280;     // +128 -> 449408
static constexpr size_t OFF_Z0HI  = 458752;     // u16 plane [28][1536][320]
static constexpr size_t SZ_Z0PL   = 6881280;    // per plane, f32 units
static constexpr size_t OFF_Z0LO  = OFF_Z0HI + SZ_Z0PL;     // 7340032
static constexpr size_t OFF_XZ    = OFF_Z0LO + SZ_Z0PL;     // 14221312
static constexpr size_t SZ_XZ     = (size_t)BB*TT*LL*256;   // 11010048
// seq buffers alias the z0 region (z0 is dead once the layer-in GEMM ran):
static constexpr size_t OFF_SEQ   = OFF_Z0HI;               // f32 [28][1536][64]
static constexpr size_t OFF_SEQHI = OFF_SEQ + (size_t)BB*TT*LL*64;   // 3211264 (u16 plane)
static constexpr size_t OFF_SEQLO = OFF_SEQHI + (size_t)BB*TT*LL*32; // 4587520
static constexpr size_t OFF_EDGE  = OFF_XZ + SZ_XZ;         // 25231360
static constexpr size_t SZ_EDGE   = (size_t)2*NBLK*2*64;
static constexpr size_t OFF_FLAGS = OFF_EDGE + SZ_EDGE;     // 25280512
// total 25,280,704 f32 = 101.1 MB (< proven 112 MB high-water)

__device__ __forceinline__ float hsig(float x) {
    return fminf(fmaxf(0.2f * x + 0.5f, 0.0f), 1.0f);
}
__device__ __forceinline__ unsigned short f2bf(float x) {
    unsigned int u = __builtin_bit_cast(unsigned int, x);
    u += 0x7fffu + ((u >> 16) & 1u);          // RNE
    return (unsigned short)(u >> 16);
}
__device__ __forceinline__ float bf2f(unsigned short h) {
    unsigned int u = ((unsigned int)h) << 16;
    return __builtin_bit_cast(float, u);
}

// ---------------------------------------------------------------------------
// prep_weights: all weight re-layouts.
// WB* : GEMM B operand, bf16 hi/lo planes, [n][k]; n = co' = f*4+g,
//       k = kh*Cpitch + ci (Cpitch: 320 layer-in w/ zero pad, 64 others).
// WHT*: scan B operand (single bf16), [n][k] n=g*F+f, k=kh*F+ci (as R9).
// biases: f32, gate-interleaved co'.
// ---------------------------------------------------------------------------
__global__ __launch_bounds__(256)
void prep_weights_kernel(const float* wx_in, const float* wh_in, const float* b_in,
                         const float* wx_r0, const float* wh_r0, const float* b_r0,
                         const float* wx_r1, const float* wh_r1, const float* b_r1,
                         const float* wx_out, const float* wh_out, const float* b_out,
                         float* __restrict__ ws)
{
    int idx = blockIdx.x * 256 + threadIdx.x;
    unsigned short* u = (unsigned short*)ws;
    if (idx < 245760) {                         // WBIN [256][960]
        int n = idx / 960, k = idx % 960;
        int kh = k / CP_IN, ci = k % CP_IN;
        float v = 0.0f;
        if (ci < CINR) {
            int f = n >> 2, g = n & 3;
            v = wx_in[((size_t)(kh * 3 + 1) * CINR + ci) * 256 + g * 64 + f];
        }
        unsigned short hi = f2bf(v);
        u[U_WBIN_HI + idx] = hi;
        u[U_WBIN_LO + idx] = f2bf(v - bf2f(hi));
        return;
    }
    idx -= 245760;
    if (idx < 49152) {                          // WBR0 [256][192]
        int n = idx / 192, k = idx % 192;
        int kh = k >> 6, ci = k & 63;
        int f = n >> 2, g = n & 3;
        float v = wx_r0[((size_t)(kh * 3 + 1) * 64 + ci) * 256 + g * 64 + f];
        unsigned short hi = f2bf(v);
        u[U_WBR0_HI + idx] = hi;
        u[U_WBR0_LO + idx] = f2bf(v - bf2f(hi));
        return;
    }
    idx -= 49152;
    if (idx < 49152) {                          // WBR1
        int n = idx / 192, k = idx % 192;
        int kh = k >> 6, ci = k & 63;
        int f = n >> 2, g = n & 3;
        float v = wx_r1[((size_t)(kh * 3 + 1) * 64 + ci) * 256 + g * 64 + f];
        unsigned short hi = f2bf(v);
        u[U_WBR1_HI + idx] = hi;
        u[U_WBR1_LO + idx] = f2bf(v - bf2f(hi));
        return;
    }
    idx -= 49152;
    if (idx < 24576) {                          // WBOUT [128][192]
        int n = idx / 192, k = idx % 192;
        int kh = k >> 6, ci = k & 63;
        int f = n >> 2, g = n & 3;
        float v = wx_out[((size_t)(kh * 3 + 1) * 64 + ci) * 128 + g * 32 + f];
        unsigned short hi = f2bf(v);
        u[U_WBOUT_HI + idx] = hi;
        u[U_WBOUT_LO + idx] = f2bf(v - bf2f(hi));
        return;
    }
    idx -= 24576;
    if (idx < 49152) {                          // WHTIN [256][192]
        int n = idx / 192, k = idx % 192, kh = k >> 6, ci = k & 63;
        u[U_WHTIN + idx] = f2bf(wh_in[((size_t)(kh * 3 + 1) * 64 + ci) * 256 + n]);
        return;
    }
    idx -= 49152;
    if (idx < 49152) {
        int n = idx / 192, k = idx % 192, kh = k >> 6, ci = k & 63;
        u[U_WHTR0 + idx] = f2bf(wh_r0[((size_t)(kh * 3 + 1) * 64 + ci) * 256 + n]);
        return;
    }
    idx -= 49152;
    if (idx < 49152) {
        int n = idx / 192, k = idx % 192, kh = k >> 6, ci = k & 63;
        u[U_WHTR1 + idx] = f2bf(wh_r1[((size_t)(kh * 3 + 1) * 64 + ci) * 256 + n]);
        return;
    }
    idx -= 49152;
    if (idx < 12288) {                          // WHTOUT [128][96]
        int n = idx / 96, k = idx % 96, kh = k / 32, ci = k % 32;
        u[U_WHTOUT + idx] = f2bf(wh_out[((size_t)(kh * 3 + 1) * 32 + ci) * 128 + n]);
        return;
    }
    idx -= 12288;
    if (idx < 256) { int f = idx >> 2, g = idx & 3; ws[OFF_BIN + idx] = b_in[g * 64 + f]; return; }
    idx -= 256;
    if (idx < 256) { int f = idx >> 2, g = idx & 3; ws[OFF_BR0 + idx] = b_r0[g * 64 + f]; return; }
    idx -= 256;
    if (idx < 256) { int f = idx >> 2, g = idx & 3; ws[OFF_BR1 + idx] = b_r1[g * 64 + f]; return; }
    idx -= 256;
    if (idx < 128) { int f = idx >> 2, g = idx & 3; ws[OFF_BOUT + idx] = b_out[g * 32 + f]; return; }
}

// ---------------------------------------------------------------------------
// build_features: gather -> z0 bf16 hi/lo planes [28][1536][320] (pad->0)
// ---------------------------------------------------------------------------
__global__ __launch_bounds__(256)
void build_features_kernel(const float* __restrict__ y,
                           const float* __restrict__ h,
                           const float* __restrict__ ev,
                           const float* __restrict__ no,
                           unsigned short* __restrict__ z0hi,
                           unsigned short* __restrict__ z0lo)
{
    long long idx = (long long)blockIdx.x * 256 + threadIdx.x;
    const long long total = (long long)BB * TT * LL * CP_IN;
    if (idx >= total) return;
    int c = (int)(idx % CP_IN);
    long long rest = idx / CP_IN;
    int l = (int)(rest % LL); rest /= LL;
    int t = (int)(rest % TT);
    int b = (int)(rest / TT);
    float v = 0.0f;
    if (c < 32) {
        int na = c >> 1, ri = c & 1;
        v = y[((((long long)b * 16 + na) * TT + t) * LL + l) * 2 + ri];
    } else if (c < 288) {
        int q = c - 32;
        int ri = q & 1, nspu = (q >> 1) & 1, nue = (q >> 2) & 3, na = q >> 4;
        v = h[((((((long long)b * 16 + na) * 4 + nue) * 2 + nspu) * TT + t) * LL + l) * 2 + ri];
    } else if (c < 296) {
        int q = c - 288; int nspu = q & 1, nue = q >> 1;
        v = ev[(((long long)(nue * 2 + nspu) * TT + t) * LL) + l];
    } else if (c == 296) {
        v = no[0];
    }
    unsigned short hi = f2bf(v);
    z0hi[idx] = hi;
    z0lo[idx] = f2bf(v - bf2f(hi));
}

// ---------------------------------------------------------------------------
// xz_gemm_mfma: out[bt][l][co'] = bias + sum_{kh,ci} A[bt][l+kh-1][ci]*W[kh][ci][co']
// Split-bf16: value = hi + lo; acc += ah*bh + ah*bl + al*bh (f32-grade).
// Block = 64 rows x 64 cols, 4 waves (wave = 16 cols x 4 m-tiles).
// A staged with +-1 halo (66 rows) per 32-ci chunk; conv taps = row shift.
// LDS pitch 40 u16 (80B): lanes m and m+8 alias 2-way (free).
// ---------------------------------------------------------------------------
__global__ __launch_bounds__(256)
void xz_gemm_mfma_kernel(const unsigned short* __restrict__ Ahi,
                         const unsigned short* __restrict__ Alo,
                         int Cpitch,
                         const unsigned short* __restrict__ Bhi,
                         const unsigned short* __restrict__ Blo,
                         const float* __restrict__ bias,
                         float* __restrict__ out, int Ncol)
{
    __shared__ unsigned short AsHi[66 * 40], AsLo[66 * 40];
    __shared__ unsigned short WsHi[3 * 64 * 40], WsLo[3 * 64 * 40];
    const int tid  = threadIdx.x;
    const int lane = tid & 63;
    const int wv   = tid >> 6;
    const int m    = lane & 15;
    const int quad = lane >> 4;
    const int bt   = blockIdx.y;
    const int l0   = blockIdx.x * 64;
    const int n0   = blockIdx.z * 64;
    const int K    = 3 * Cpitch;
    const int NC   = Cpitch >> 5;

    floatx4 acc[4];
#pragma unroll
    for (int i = 0; i < 4; i++) acc[i] = (floatx4){0.f, 0.f, 0.f, 0.f};

    for (int cc = 0; cc < NC; ++cc) {
        __syncthreads();
        // stage A rows l0-1 .. l0+64, 32 ci (4 groups of 8)
        for (int i = tid; i < 66 * 4; i += 256) {
            int r = i >> 2, c8 = (i & 3) * 8;
            int row = l0 + r - 1;
            short8 vh = (short8)0, vl = (short8)0;
            if (row >= 0 && row < LL) {
                size_t off = ((size_t)bt * LL + row) * Cpitch + cc * 32 + c8;
                vh = *reinterpret_cast<const short8*>(&Ahi[off]);
                vl = *reinterpret_cast<const short8*>(&Alo[off]);
            }
            *reinterpret_cast<short8*>(&AsHi[r * 40 + c8]) = vh;
            *reinterpret_cast<short8*>(&AsLo[r * 40 + c8]) = vl;
        }
        // stage B: 3 kh x 64 n x 32 k
        for (int i = tid; i < 3 * 64 * 4; i += 256) {
            int kh = i >> 8;
            int r2 = i & 255;
            int n = r2 >> 2, c8 = (r2 & 3) * 8;
            size_t off = (size_t)(n0 + n) * K + kh * Cpitch + cc * 32 + c8;
            *reinterpret_cast<short8*>(&WsHi[(kh * 64 + n) * 40 + c8]) =
                *reinterpret_cast<const short8*>(&Bhi[off]);
            *reinterpret_cast<short8*>(&WsLo[(kh * 64 + n) * 40 + c8]) =
                *reinterpret_cast<const short8*>(&Blo[off]);
        }
        __syncthreads();
#pragma unroll
        for (int kh = 0; kh < 3; ++kh) {
            const int bofs = (kh * 64 + wv * 16 + m) * 40 + quad * 8;
            const short8 bh = *reinterpret_cast<const short8*>(&WsHi[bofs]);
            const short8 bl = *reinterpret_cast<const short8*>(&WsLo[bofs]);
#pragma unroll
            for (int mt = 0; mt < 4; ++mt) {
                const int aofs = (mt * 16 + m + kh) * 40 + quad * 8;
                const short8 ah = *reinterpret_cast<const short8*>(&AsHi[aofs]);
                const short8 al = *reinterpret_cast<const short8*>(&AsLo[aofs]);
                acc[mt] = __builtin_amdgcn_mfma_f32_16x16x32_bf16(al, bh, acc[mt], 0, 0, 0);
                acc[mt] = __builtin_amdgcn_mfma_f32_16x16x32_bf16(ah, bl, acc[mt], 0, 0, 0);
                acc[mt] = __builtin_amdgcn_mfma_f32_16x16x32_bf16(ah, bh, acc[mt], 0, 0, 0);
            }
        }
    }
    // epilogue: C layout col = lane&15, row = quad*4+reg
    const int col = n0 + wv * 16 + m;
    const float bv = bias[col];
#pragma unroll
    for (int mt = 0; mt < 4; ++mt) {
#pragma unroll
        for (int reg = 0; reg < 4; ++reg) {
            int l = l0 + mt * 16 + quad * 4 + reg;
            out[((size_t)bt * LL + l) * Ncol + col] = acc[mt][reg] + bv;
        }
    }
}

// ---------------------------------------------------------------------------
// lstm_scan (MFMA, from R9, verified): 14 steps in one launch; Wh bf16
// B-fragments register-resident across the scan; h recurrence bf16 in LDS;
// c f32 in registers; strip edges via device-scope atomics + flag spin.
// NEW: also emits bf16 hi/lo planes of the layer output for the next GEMM.
// ---------------------------------------------------------------------------
template <int F_, bool RESID, bool OUTW>
__global__ __launch_bounds__(64 * (F_ / 16))
void lstm_scan_kernel(const float* __restrict__ xz,           // [28][1536][4F] co'=f*4+g
                      const unsigned short* __restrict__ WhT, // [4F][3F] bf16
                      float* seq,                             // f32 layer in/out (or null)
                      unsigned short* __restrict__ seqhb,     // bf16 hi out (or null)
                      unsigned short* __restrict__ seqlb,     // bf16 lo out (or null)
                      float* __restrict__ dout,               // final out (or null)
                      float* __restrict__ edge,               // [2][NBLK][2][64] f32
                      int* __restrict__ flags,                // [NBLK]
                      int layer)
{
    constexpr int NW = F_ / 16;
    constexpr int NT = 64 * NW;
    constexpr int K  = 3 * F_;
    constexpr int KS = K / 32;
    constexpr int KH = KS / 3;
    constexpr int HP = F_ + 8;
    __shared__ unsigned short Hs[2][18 * HP];

    const int tid  = threadIdx.x;
    const int lane = tid & 63;
    const int wv   = tid >> 6;
    const int m    = lane & 15;
    const int quad = lane >> 4;
    const int fw0  = wv * 16;
    const int blk  = blockIdx.x;
    const int b    = blk / NSTRIP;
    const int strip = blk % NSTRIP;
    const int l0   = strip * 16;
    const int f    = fw0 + m;

    short8 bf[4][KS];
#pragma unroll
    for (int g = 0; g < 4; g++)
#pragma unroll
        for (int ks = 0; ks < KS; ks++) {
            const int n  = g * F_ + fw0 + m;
            const int k0 = ks * 32 + quad * 8;
            bf[g][ks] = *reinterpret_cast<const short8*>(&WhT[(size_t)n * K + k0]);
        }

    for (int idx = tid; idx < 18 * HP; idx += NT) { Hs[0][idx] = 0; Hs[1][idx] = 0; }
    __syncthreads();

    float c[4] = {0.f, 0.f, 0.f, 0.f};
    int cur = 0;
    for (int t = 0; t < TT; ++t) {
        floatx4 zi = {0.f, 0.f, 0.f, 0.f};
        floatx4 zf = {0.f, 0.f, 0.f, 0.f};
        floatx4 zg = {0.f, 0.f, 0.f, 0.f};
        floatx4 zo = {0.f, 0.f, 0.f, 0.f};

        if (t > 0) {
            const int target = layer * TT + t;
            if (tid == 0 && strip > 0) {
                while (__hip_atomic_load(&flags[blk - 1], __ATOMIC_ACQUIRE,
                                         __HIP_MEMORY_SCOPE_AGENT) < target)
                    __builtin_amdgcn_s_sleep(1);
            }
            if (tid == 1 && strip < NSTRIP - 1) {
                while (__hip_atomic_load(&flags[blk + 1], __ATOMIC_ACQUIRE,
                                         __HIP_MEMORY_SCOPE_AGENT) < target)
                    __builtin_amdgcn_s_sleep(1);
            }
            __syncthreads();
            const int par = (t - 1) & 1;
            if (tid < F_) {
                float v = 0.0f;
                if (strip > 0)
                    v = __hip_atomic_load(
                        &edge[(((size_t)par * NBLK + (blk - 1)) * 2 + 1) * 64 + tid],
                        __ATOMIC_RELAXED, __HIP_MEMORY_SCOPE_AGENT);
                Hs[cur][0 * HP + tid] = f2bf(v);
            } else if (tid < 2 * F_) {
                int ff = tid - F_;
                float v = 0.0f;
                if (strip < NSTRIP - 1)
                    v = __hip_atomic_load(
                        &edge[(((size_t)par * NBLK + (blk + 1)) * 2 + 0) * 64 + ff],
                        __ATOMIC_RELAXED, __HIP_MEMORY_SCOPE_AGENT);
                Hs[cur][17 * HP + ff] = f2bf(v);
            }
            __syncthreads();

#pragma unroll
            for (int kh = 0; kh < 3; kh++) {
#pragma unroll
                for (int hf = 0; hf < KH; hf++) {
                    const short8 af = *reinterpret_cast<const short8*>(
                        &Hs[cur][(m + kh) * HP + hf * 32 + quad * 8]);
                    const int ks = kh * KH + hf;
                    zi = __builtin_amdgcn_mfma_f32_16x16x32_bf16(af, bf[0][ks], zi, 0, 0, 0);
                    zf = __builtin_amdgcn_mfma_f32_16x16x32_bf16(af, bf[1][ks], zf, 0, 0, 0);
                    zg = __builtin_amdgcn_mfma_f32_16x16x32_bf16(af, bf[2][ks], zg, 0, 0, 0);
                    zo = __builtin_amdgcn_mfma_f32_16x16x32_bf16(af, bf[3][ks], zo, 0, 0, 0);
                }
            }
        }

        const size_t btL = ((size_t)b * TT + t) * LL;
        const int nxt = cur ^ 1;
        const int parw = t & 1;
#pragma unroll
        for (int reg = 0; reg < 4; reg++) {
            const int r = quad * 4 + reg;
            const int l = l0 + r;
            const float4 z4 = *reinterpret_cast<const float4*>(
                &xz[(btL + l) * (size_t)(4 * F_) + f * 4]);
            const float vzi = z4.x + zi[reg];
            const float vzf = z4.y + zf[reg];
            const float vzg = z4.z + zg[reg];
            const float vzo = z4.w + zo[reg];
            const float ig = hsig(vzi), fg = hsig(vzf);
            const float gg = tanhf(vzg), og = hsig(vzo);
            const float cn = fg * c[reg] + ig * gg;
            const float hn = og * tanhf(cn);
            c[reg] = cn;
            Hs[nxt][(1 + r) * HP + f] = f2bf(hn);
            if (r == 0)
                __hip_atomic_store(
                    &edge[(((size_t)parw * NBLK + blk) * 2 + 0) * 64 + f], hn,
                    __ATOMIC_RELAXED, __HIP_MEMORY_SCOPE_AGENT);
            if (r == 15)
                __hip_atomic_store(
                    &edge[(((size_t)parw * NBLK + blk) * 2 + 1) * 64 + f], hn,
                    __ATOMIC_RELAXED, __HIP_MEMORY_SCOPE_AGENT);
            if (OUTW) {
                const int ue = f >> 3, spu = (f >> 2) & 1, bit = f & 3;
                const size_t n = (size_t)t * LL + l;
                dout[(((size_t)b * 4 + ue) * 2 + spu) * ((size_t)TT * LL * 4) + n * 4 + bit] = hn;
            } else {
                float v = hn;
                if (RESID) v += seq[(btL + l) * F_ + f];   // same idx, same thread
                seq[(btL + l) * F_ + f] = v;
                const unsigned short hi = f2bf(v);
                seqhb[(btL + l) * F_ + f] = hi;
                seqlb[(btL + l) * F_ + f] = f2bf(v - bf2f(hi));
            }
        }
        __syncthreads();      // drains LDS + global stores before publication
        if (tid == 0)
            __hip_atomic_store(&flags[blk], layer * TT + t + 1,
                               __ATOMIC_RELEASE, __HIP_MEMORY_SCOPE_AGENT);
        cur = nxt;
    }
}

// ---------------------------------------------------------------------------
extern "C" void kernel_launch(void* const* d_in, const int* in_sizes, int n_in,
                              void* d_out, int out_size, void* d_ws, size_t ws_size,
                              hipStream_t stream)
{
    (void)in_sizes; (void)n_in; (void)out_size; (void)ws_size;
    const float* y_ri   = (const float*)d_in[0];
    const float* h_ri   = (const float*)d_in[1];
    const float* evar   = (const float*)d_in[2];
    const float* no     = (const float*)d_in[3];
    const float* wx_in  = (const float*)d_in[4];
    const float* wh_in  = (const float*)d_in[5];
    const float* b_in   = (const float*)d_in[6];
    const float* wx_r0  = (const float*)d_in[7];
    const float* wh_r0  = (const float*)d_in[8];
    const float* b_r0   = (const float*)d_in[9];
    const float* wx_r1  = (const float*)d_in[10];
    const float* wh_r1  = (const float*)d_in[11];
    const float* b_r1   = (const float*)d_in[12];
    const float* wx_out = (const float*)d_in[13];
    const float* wh_out = (const float*)d_in[14];
    const float* b_out  = (const float*)d_in[15];

    float* ws = (float*)d_ws;
    unsigned short* wu = (unsigned short*)d_ws;
    float* dout = (float*)d_out;

    {
        // total prep items = 529280 -> 2068 blocks
        prep_weights_kernel<<<2068, 256, 0, stream>>>(
            wx_in, wh_in, b_in, wx_r0, wh_r0, b_r0,
            wx_r1, wh_r1, b_r1, wx_out, wh_out, b_out, ws);
    }
    {
        long long total = (long long)BB * TT * LL * CP_IN;   // 13,762,560
        int blocks = (int)((total + 255) / 256);
        build_features_kernel<<<blocks, 256, 0, stream>>>(
            y_ri, h_ri, evar, no,
            (unsigned short*)(ws + OFF_Z0HI), (unsigned short*)(ws + OFF_Z0LO));
    }
    hipMemsetAsync(ws + OFF_FLAGS, 0, NBLK * sizeof(int), stream);

    float* xz    = ws + OFF_XZ;
    float* seq   = ws + OFF_SEQ;
    unsigned short* seqhb = (unsigned short*)(ws + OFF_SEQHI);
    unsigned short* seqlb = (unsigned short*)(ws + OFF_SEQLO);
    float* edge  = ws + OFF_EDGE;
    int*   flags = (int*)(ws + OFF_FLAGS);

    const dim3 gIn(LL / 64, BB * TT, 4);    // N=256
    const dim3 gR (LL / 64, BB * TT, 4);
    const dim3 gO (LL / 64, BB * TT, 2);    // N=128

    // ---- layer in: Cin=297(p320) -> F=64
    xz_gemm_mfma_kernel<<<gIn, 256, 0, stream>>>(
        (unsigned short*)(ws + OFF_Z0HI), (unsigned short*)(ws + OFF_Z0LO), CP_IN,
        wu + U_WBIN_HI, wu + U_WBIN_LO, ws + OFF_BIN, xz, 256);
    lstm_scan_kernel<64, false, false><<<NBLK, 256, 0, stream>>>(
        xz, wu + U_WHTIN, seq, seqhb, seqlb, nullptr, edge, flags, 0);

    // ---- layer r0 (+residual, in-place on seq)
    xz_gemm_mfma_kernel<<<gR, 256, 0, stream>>>(
        seqhb, seqlb, 64, wu + U_WBR0_HI, wu + U_WBR0_LO, ws + OFF_BR0, xz, 256);
    lstm_scan_kernel<64, true, false><<<NBLK, 256, 0, stream>>>(
        xz, wu + U_WHTR0, seq, seqhb, seqlb, nullptr, edge, flags, 1);

    // ---- layer r1 (+residual, in-place on seq)
    xz_gemm_mfma_kernel<<<gR, 256, 0, stream>>>(
        seqhb, seqlb, 64, wu + U_WBR1_HI, wu + U_WBR1_LO, ws + OFF_BR1, xz, 256);
    lstm_scan_kernel<64, true, false><<<NBLK, 256, 0, stream>>>(
        xz, wu + U_WHTR1, seq, seqhb, seqlb, nullptr, edge, flags, 2);

    // ---- layer out: F=32, writes d_out (f32, transposed layout)
    xz_gemm_mfma_kernel<<<gO, 256, 0, stream>>>(
        seqhb, seqlb, 64, wu + U_WBOUT_HI, wu + U_WBOUT_LO, ws + OFF_BOUT, xz, 128);
    lstm_scan_kernel<32, false, true><<<NBLK, 128, 0, stream>>>(
        xz, wu + U_WHTOUT, nullptr, nullptr, nullptr, dout, edge, flags, 3);
}

// Round 11
// 516.150 us; speedup vs baseline: 2.7346x; 1.8639x over previous
//
#include <hip/hip_runtime.h>
#include <hip/hip_bf16.h>

// ---------------------------------------------------------------------------
// PUSCH neural detector: 4 stacked ConvLSTM layers on [B=2,T=14,H=1536,W=1].
// 3x3 conv degenerates to width-3 conv along H (kw=1 slice).
// Round 11: trapezoidal scan — each block redundantly computes a 48-row
// window so its own 16-row strip is correct for all 14 steps with ZERO
// inter-block communication (R10 counters: scans were sync-latency-bound at
// VALUBusy 3.9%). MFMA scan w/ register-resident Wh (R9) + split-bf16 MFMA
// GEMMs (R10) retained.
// ---------------------------------------------------------------------------

#define BB   2
#define TT   14
#define LL   1536
#define CINR 297
#define CP_IN 320                 // padded input channels (10 chunks of 32)
#define NSTRIP 96                 // LL / 16
#define NBLK  (BB * NSTRIP)       // 192 scan blocks
#define WIN  48                   // scan window rows (own 16 + 16 halo each side)

typedef __attribute__((ext_vector_type(8))) short short8;   // 8 bf16 = 4 VGPRs
typedef __attribute__((ext_vector_type(4))) float floatx4;  // MFMA C/D

// ---- workspace layout -----------------------------------------------------
static constexpr size_t U_WBIN_HI  = 0;         // [256][960]
static constexpr size_t U_WBIN_LO  = 245760;
static constexpr size_t U_WBR0_HI  = 491520;    // [256][192]
static constexpr size_t U_WBR0_LO  = 540672;
static constexpr size_t U_WBR1_HI  = 589824;
static constexpr size_t U_WBR1_LO  = 638976;
static constexpr size_t U_WBOUT_HI = 688128;    // [128][192]
static constexpr size_t U_WBOUT_LO = 712704;
static constexpr size_t U_WHTIN    = 737280;    // [256][192] scan WhT bf16
static constexpr size_t U_WHTR0    = 786432;
static constexpr size_t U_WHTR1    = 835584;
static constexpr size_t U_WHTOUT   = 884736;    // [128][96]
static constexpr size_t OFF_BIN   = 448512;     // f32 gate-interleaved biases
static constexpr size_t OFF_BR0   = 448768;
static constexpr size_t OFF_BR1   = 449024;
static constexpr size_t OFF_BOUT  = 449280;
static constexpr size_t OFF_Z0HI  = 458752;     // u16 plane [28][1536][320]
static constexpr size_t SZ_Z0PL   = 6881280;
static constexpr size_t OFF_Z0LO  = OFF_Z0HI + SZ_Z0PL;
static constexpr size_t OFF_XZ    = OFF_Z0LO + SZ_Z0PL;
static constexpr size_t SZ_XZ     = (size_t)BB*TT*LL*256;
// seq aliases the dead z0 region after the layer-in GEMM:
static constexpr size_t OFF_SEQ   = OFF_Z0HI;               // f32 [28][1536][64]
static constexpr size_t OFF_SEQHI = OFF_SEQ + (size_t)BB*TT*LL*64;
static constexpr size_t OFF_SEQLO = OFF_SEQHI + (size_t)BB*TT*LL*32;
// total ~101 MB

__device__ __forceinline__ float hsig(float x) {
    return fminf(fmaxf(0.2f * x + 0.5f, 0.0f), 1.0f);
}
__device__ __forceinline__ float ftanh(float x) {
    // tanh(x) = 1 - 2/(e^{2x}+1); bounded, finite-in -> finite-out.
    float e = __expf(2.0f * x);
    return 1.0f - 2.0f / (e + 1.0f);
}
__device__ __forceinline__ unsigned short f2bf(float x) {
    unsigned int u = __builtin_bit_cast(unsigned int, x);
    u += 0x7fffu + ((u >> 16) & 1u);          // RNE
    return (unsigned short)(u >> 16);
}
__device__ __forceinline__ float bf2f(unsigned short h) {
    unsigned int u = ((unsigned int)h) << 16;
    return __builtin_bit_cast(float, u);
}

// ---------------------------------------------------------------------------
// prep_weights (unchanged from R10).
// ---------------------------------------------------------------------------
__global__ __launch_bounds__(256)
void prep_weights_kernel(const float* wx_in, const float* wh_in, const float* b_in,
                         const float* wx_r0, const float* wh_r0, const float* b_r0,
                         const float* wx_r1, const float* wh_r1, const float* b_r1,
                         const float* wx_out, const float* wh_out, const float* b_out,
                         float* __restrict__ ws)
{
    int idx = blockIdx.x * 256 + threadIdx.x;
    unsigned short* u = (unsigned short*)ws;
    if (idx < 245760) {                         // WBIN [256][960]
        int n = idx / 960, k = idx % 960;
        int kh = k / CP_IN, ci = k % CP_IN;
        float v = 0.0f;
        if (ci < CINR) {
            int f = n >> 2, g = n & 3;
            v = wx_in[((size_t)(kh * 3 + 1) * CINR + ci) * 256 + g * 64 + f];
        }
        unsigned short hi = f2bf(v);
        u[U_WBIN_HI + idx] = hi;
        u[U_WBIN_LO + idx] = f2bf(v - bf2f(hi));
        return;
    }
    idx -= 245760;
    if (idx < 49152) {                          // WBR0 [256][192]
        int n = idx / 192, k = idx % 192;
        int kh = k >> 6, ci = k & 63;
        int f = n >> 2, g = n & 3;
        float v = wx_r0[((size_t)(kh * 3 + 1) * 64 + ci) * 256 + g * 64 + f];
        unsigned short hi = f2bf(v);
        u[U_WBR0_HI + idx] = hi;
        u[U_WBR0_LO + idx] = f2bf(v - bf2f(hi));
        return;
    }
    idx -= 49152;
    if (idx < 49152) {                          // WBR1
        int n = idx / 192, k = idx % 192;
        int kh = k >> 6, ci = k & 63;
        int f = n >> 2, g = n & 3;
        float v = wx_r1[((size_t)(kh * 3 + 1) * 64 + ci) * 256 + g * 64 + f];
        unsigned short hi = f2bf(v);
        u[U_WBR1_HI + idx] = hi;
        u[U_WBR1_LO + idx] = f2bf(v - bf2f(hi));
        return;
    }
    idx -= 49152;
    if (idx < 24576) {                          // WBOUT [128][192]
        int n = idx / 192, k = idx % 192;
        int kh = k >> 6, ci = k & 63;
        int f = n >> 2, g = n & 3;
        float v = wx_out[((size_t)(kh * 3 + 1) * 64 + ci) * 128 + g * 32 + f];
        unsigned short hi = f2bf(v);
        u[U_WBOUT_HI + idx] = hi;
        u[U_WBOUT_LO + idx] = f2bf(v - bf2f(hi));
        return;
    }
    idx -= 24576;
    if (idx < 49152) {                          // WHTIN [256][192]
        int n = idx / 192, k = idx % 192, kh = k >> 6, ci = k & 63;
        u[U_WHTIN + idx] = f2bf(wh_in[((size_t)(kh * 3 + 1) * 64 + ci) * 256 + n]);
        return;
    }
    idx -= 49152;
    if (idx < 49152) {
        int n = idx / 192, k = idx % 192, kh = k >> 6, ci = k & 63;
        u[U_WHTR0 + idx] = f2bf(wh_r0[((size_t)(kh * 3 + 1) * 64 + ci) * 256 + n]);
        return;
    }
    idx -= 49152;
    if (idx < 49152) {
        int n = idx / 192, k = idx % 192, kh = k >> 6, ci = k & 63;
        u[U_WHTR1 + idx] = f2bf(wh_r1[((size_t)(kh * 3 + 1) * 64 + ci) * 256 + n]);
        return;
    }
    idx -= 49152;
    if (idx < 12288) {                          // WHTOUT [128][96]
        int n = idx / 96, k = idx % 96, kh = k / 32, ci = k % 32;
        u[U_WHTOUT + idx] = f2bf(wh_out[((size_t)(kh * 3 + 1) * 32 + ci) * 128 + n]);
        return;
    }
    idx -= 12288;
    if (idx < 256) { int f = idx >> 2, g = idx & 3; ws[OFF_BIN + idx] = b_in[g * 64 + f]; return; }
    idx -= 256;
    if (idx < 256) { int f = idx >> 2, g = idx & 3; ws[OFF_BR0 + idx] = b_r0[g * 64 + f]; return; }
    idx -= 256;
    if (idx < 256) { int f = idx >> 2, g = idx & 3; ws[OFF_BR1 + idx] = b_r1[g * 64 + f]; return; }
    idx -= 256;
    if (idx < 128) { int f = idx >> 2, g = idx & 3; ws[OFF_BOUT + idx] = b_out[g * 32 + f]; return; }
}

// ---------------------------------------------------------------------------
// build_features (unchanged from R10): gather -> z0 bf16 hi/lo [28][1536][320]
// ---------------------------------------------------------------------------
__global__ __launch_bounds__(256)
void build_features_kernel(const float* __restrict__ y,
                           const float* __restrict__ h,
                           const float* __restrict__ ev,
                           const float* __restrict__ no,
                           unsigned short* __restrict__ z0hi,
                           unsigned short* __restrict__ z0lo)
{
    long long idx = (long long)blockIdx.x * 256 + threadIdx.x;
    const long long total = (long long)BB * TT * LL * CP_IN;
    if (idx >= total) return;
    int c = (int)(idx % CP_IN);
    long long rest = idx / CP_IN;
    int l = (int)(rest % LL); rest /= LL;
    int t = (int)(rest % TT);
    int b = (int)(rest / TT);
    float v = 0.0f;
    if (c < 32) {
        int na = c >> 1, ri = c & 1;
        v = y[((((long long)b * 16 + na) * TT + t) * LL + l) * 2 + ri];
    } else if (c < 288) {
        int q = c - 32;
        int ri = q & 1, nspu = (q >> 1) & 1, nue = (q >> 2) & 3, na = q >> 4;
        v = h[((((((long long)b * 16 + na) * 4 + nue) * 2 + nspu) * TT + t) * LL + l) * 2 + ri];
    } else if (c < 296) {
        int q = c - 288; int nspu = q & 1, nue = q >> 1;
        v = ev[(((long long)(nue * 2 + nspu) * TT + t) * LL) + l];
    } else if (c == 296) {
        v = no[0];
    }
    unsigned short hi = f2bf(v);
    z0hi[idx] = hi;
    z0lo[idx] = f2bf(v - bf2f(hi));
}

// ---------------------------------------------------------------------------
// xz_gemm_mfma (unchanged from R10): split-bf16 MFMA conv-GEMM.
// ---------------------------------------------------------------------------
__global__ __launch_bounds__(256)
void xz_gemm_mfma_kernel(const unsigned short* __restrict__ Ahi,
                         const unsigned short* __restrict__ Alo,
                         int Cpitch,
                         const unsigned short* __restrict__ Bhi,
                         const unsigned short* __restrict__ Blo,
                         const float* __restrict__ bias,
                         float* __restrict__ out, int Ncol)
{
    __shared__ unsigned short AsHi[66 * 40], AsLo[66 * 40];
    __shared__ unsigned short WsHi[3 * 64 * 40], WsLo[3 * 64 * 40];
    const int tid  = threadIdx.x;
    const int lane = tid & 63;
    const int wv   = tid >> 6;
    const int m    = lane & 15;
    const int quad = lane >> 4;
    const int bt   = blockIdx.y;
    const int l0   = blockIdx.x * 64;
    const int n0   = blockIdx.z * 64;
    const int K    = 3 * Cpitch;
    const int NC   = Cpitch >> 5;

    floatx4 acc[4];
#pragma unroll
    for (int i = 0; i < 4; i++) acc[i] = (floatx4){0.f, 0.f, 0.f, 0.f};

    for (int cc = 0; cc < NC; ++cc) {
        __syncthreads();
        for (int i = tid; i < 66 * 4; i += 256) {
            int r = i >> 2, c8 = (i & 3) * 8;
            int row = l0 + r - 1;
            short8 vh = (short8)0, vl = (short8)0;
            if (row >= 0 && row < LL) {
                size_t off = ((size_t)bt * LL + row) * Cpitch + cc * 32 + c8;
                vh = *reinterpret_cast<const short8*>(&Ahi[off]);
                vl = *reinterpret_cast<const short8*>(&Alo[off]);
            }
            *reinterpret_cast<short8*>(&AsHi[r * 40 + c8]) = vh;
            *reinterpret_cast<short8*>(&AsLo[r * 40 + c8]) = vl;
        }
        for (int i = tid; i < 3 * 64 * 4; i += 256) {
            int kh = i >> 8;
            int r2 = i & 255;
            int n = r2 >> 2, c8 = (r2 & 3) * 8;
            size_t off = (size_t)(n0 + n) * K + kh * Cpitch + cc * 32 + c8;
            *reinterpret_cast<short8*>(&WsHi[(kh * 64 + n) * 40 + c8]) =
                *reinterpret_cast<const short8*>(&Bhi[off]);
            *reinterpret_cast<short8*>(&WsLo[(kh * 64 + n) * 40 + c8]) =
                *reinterpret_cast<const short8*>(&Blo[off]);
        }
        __syncthreads();
#pragma unroll
        for (int kh = 0; kh < 3; ++kh) {
            const int bofs = (kh * 64 + wv * 16 + m) * 40 + quad * 8;
            const short8 bh = *reinterpret_cast<const short8*>(&WsHi[bofs]);
            const short8 bl = *reinterpret_cast<const short8*>(&WsLo[bofs]);
#pragma unroll
            for (int mt = 0; mt < 4; ++mt) {
                const int aofs = (mt * 16 + m + kh) * 40 + quad * 8;
                const short8 ah = *reinterpret_cast<const short8*>(&AsHi[aofs]);
                const short8 al = *reinterpret_cast<const short8*>(&AsLo[aofs]);
                acc[mt] = __builtin_amdgcn_mfma_f32_16x16x32_bf16(al, bh, acc[mt], 0, 0, 0);
                acc[mt] = __builtin_amdgcn_mfma_f32_16x16x32_bf16(ah, bl, acc[mt], 0, 0, 0);
                acc[mt] = __builtin_amdgcn_mfma_f32_16x16x32_bf16(ah, bh, acc[mt], 0, 0, 0);
            }
        }
    }
    const int col = n0 + wv * 16 + m;
    const float bv = bias[col];
#pragma unroll
    for (int mt = 0; mt < 4; ++mt) {
#pragma unroll
        for (int reg = 0; reg < 4; ++reg) {
            int l = l0 + mt * 16 + quad * 4 + reg;
            out[((size_t)bt * LL + l) * Ncol + col] = acc[mt][reg] + bv;
        }
    }
}

// ---------------------------------------------------------------------------
// lstm_scan v3 (trapezoid): 14 steps, ZERO inter-block sync.
// Block owns 16 rows; computes a 48-row window [o0-16, o0+32). h_t is exact
// on window rows [t, 48-t) (creep 1 row/step from the zero halo); own rows
// [16,32) stay inside the frontier for all t<=13. Garbage rows are bounded
// (|h|<=1, xz masked to 0 outside frontier/image) -> no NaN, no pollution of
// valid rows (MFMA row m only reads h rows m..m+2, same creep).
// Wh bf16 B-frags register-resident (R9); h ping-pong bf16 in LDS (halo
// slots permanently 0 = conv pad); c f32 in registers; one barrier/step.
// ---------------------------------------------------------------------------
template <int F_, bool RESID, bool OUTW>
__global__ __launch_bounds__(64 * (F_ / 16))
void lstm_scan_kernel(const float* __restrict__ xz,           // [28][1536][4F] co'=f*4+g
                      const unsigned short* __restrict__ WhT, // [4F][3F] bf16
                      float* seq,                             // f32 layer in/out (or null)
                      unsigned short* __restrict__ seqhb,     // bf16 hi out (or null)
                      unsigned short* __restrict__ seqlb,     // bf16 lo out (or null)
                      float* __restrict__ dout)               // final out (or null)
{
    constexpr int NW = F_ / 16;
    constexpr int NT = 64 * NW;
    constexpr int K  = 3 * F_;
    constexpr int KS = K / 32;          // 6 (F=64) / 3 (F=32)
    constexpr int KH = KS / 3;          // 2 / 1
    constexpr int HP = F_ + 8;
    __shared__ unsigned short Hs[2][(WIN + 2) * HP];

    const int tid  = threadIdx.x;
    const int lane = tid & 63;
    const int wv   = tid >> 6;
    const int m    = lane & 15;
    const int quad = lane >> 4;
    const int blk  = blockIdx.x;
    const int b    = blk / NSTRIP;
    const int o0   = (blk % NSTRIP) * 16;   // own rows [o0, o0+16)
    const int f    = wv * 16 + m;

    // B-fragments resident for the whole scan
    short8 bfr[4][KS];
#pragma unroll
    for (int g = 0; g < 4; g++)
#pragma unroll
        for (int ks = 0; ks < KS; ks++) {
            const int n  = g * F_ + f;
            const int k0 = ks * 32 + quad * 8;
            bfr[g][ks] = *reinterpret_cast<const short8*>(&WhT[(size_t)n * K + k0]);
        }

    for (int idx = tid; idx < (WIN + 2) * HP; idx += NT) {
        Hs[0][idx] = 0; Hs[1][idx] = 0;     // halo slots stay 0 forever
    }
    __syncthreads();

    float c[3][4];
#pragma unroll
    for (int i = 0; i < 3; i++)
#pragma unroll
        for (int j = 0; j < 4; j++) c[i][j] = 0.0f;

    int cur = 0;
    for (int t = 0; t < TT; ++t) {
        const size_t btL = ((size_t)b * TT + t) * LL;

        // prefetch xz for the whole step (predicated: image bounds + frontier)
        float4 xzv[3][4];
        float  rsv[4];
#pragma unroll
        for (int mt = 0; mt < 3; ++mt)
#pragma unroll
            for (int reg = 0; reg < 4; ++reg) {
                const int w = mt * 16 + quad * 4 + reg;
                const int l = o0 - 16 + w;
                float4 v = make_float4(0.f, 0.f, 0.f, 0.f);
                if (l >= 0 && l < LL && w >= t && w < WIN - t)
                    v = *reinterpret_cast<const float4*>(
                        &xz[(btL + l) * (size_t)(4 * F_) + f * 4]);
                xzv[mt][reg] = v;
            }
        if (RESID) {
#pragma unroll
            for (int reg = 0; reg < 4; ++reg) {
                const int l = o0 + quad * 4 + reg;          // own rows (mt=1)
                rsv[reg] = seq[(btL + l) * F_ + f];
            }
        }

        const int nxt = cur ^ 1;
#pragma unroll
        for (int mt = 0; mt < 3; ++mt) {
            floatx4 zi = {0.f, 0.f, 0.f, 0.f};
            floatx4 zf = {0.f, 0.f, 0.f, 0.f};
            floatx4 zg = {0.f, 0.f, 0.f, 0.f};
            floatx4 zo = {0.f, 0.f, 0.f, 0.f};
            if (t > 0) {
#pragma unroll
                for (int kh = 0; kh < 3; kh++) {
#pragma unroll
                    for (int hf = 0; hf < KH; hf++) {
                        const short8 af = *reinterpret_cast<const short8*>(
                            &Hs[cur][(mt * 16 + m + kh) * HP + hf * 32 + quad * 8]);
                        const int ks = kh * KH + hf;
                        zi = __builtin_amdgcn_mfma_f32_16x16x32_bf16(af, bfr[0][ks], zi, 0, 0, 0);
                        zf = __builtin_amdgcn_mfma_f32_16x16x32_bf16(af, bfr[1][ks], zf, 0, 0, 0);
                        zg = __builtin_amdgcn_mfma_f32_16x16x32_bf16(af, bfr[2][ks], zg, 0, 0, 0);
                        zo = __builtin_amdgcn_mfma_f32_16x16x32_bf16(af, bfr[3][ks], zo, 0, 0, 0);
                    }
                }
            }
#pragma unroll
            for (int reg = 0; reg < 4; ++reg) {
                const int w = mt * 16 + quad * 4 + reg;
                const int l = o0 - 16 + w;
                const bool valid = (l >= 0 && l < LL);
                const float4 z4 = xzv[mt][reg];
                const float ig = hsig(z4.x + zi[reg]);
                const float fg = hsig(z4.y + zf[reg]);
                const float gg = ftanh(z4.z + zg[reg]);
                const float og = hsig(z4.w + zo[reg]);
                float cn = fg * c[mt][reg] + ig * gg;
                float hn = og * ftanh(cn);
                if (!valid) { cn = 0.0f; hn = 0.0f; }   // exact conv pad
                c[mt][reg] = cn;
                Hs[nxt][(1 + w) * HP + f] = f2bf(hn);
                if (w >= 16 && w < 32) {                // own rows -> outputs
                    if (OUTW) {
                        const int ue = f >> 3, spu = (f >> 2) & 1, bit = f & 3;
                        const size_t n = (size_t)t * LL + l;
                        dout[(((size_t)b * 4 + ue) * 2 + spu) * ((size_t)TT * LL * 4)
                             + n * 4 + bit] = hn;
                    } else {
                        float v = hn;
                        if (RESID) v += rsv[reg];
                        seq[(btL + l) * F_ + f] = v;
                        const unsigned short hi = f2bf(v);
                        seqhb[(btL + l) * F_ + f] = hi;
                        seqlb[(btL + l) * F_ + f] = f2bf(v - bf2f(hi));
                    }
                }
            }
        }
        __syncthreads();        // Hs[nxt] complete before next step reads it
        cur = nxt;
    }
}

// ---------------------------------------------------------------------------
extern "C" void kernel_launch(void* const* d_in, const int* in_sizes, int n_in,
                              void* d_out, int out_size, void* d_ws, size_t ws_size,
                              hipStream_t stream)
{
    (void)in_sizes; (void)n_in; (void)out_size; (void)ws_size;
    const float* y_ri   = (const float*)d_in[0];
    const float* h_ri   = (const float*)d_in[1];
    const float* evar   = (const float*)d_in[2];
    const float* no     = (const float*)d_in[3];
    const float* wx_in  = (const float*)d_in[4];
    const float* wh_in  = (const float*)d_in[5];
    const float* b_in   = (const float*)d_in[6];
    const float* wx_r0  = (const float*)d_in[7];
    const float* wh_r0  = (const float*)d_in[8];
    const float* b_r0   = (const float*)d_in[9];
    const float* wx_r1  = (const float*)d_in[10];
    const float* wh_r1  = (const float*)d_in[11];
    const float* b_r1   = (const float*)d_in[12];
    const float* wx_out = (const float*)d_in[13];
    const float* wh_out = (const float*)d_in[14];
    const float* b_out  = (const float*)d_in[15];

    float* ws = (float*)d_ws;
    unsigned short* wu = (unsigned short*)d_ws;
    float* dout = (float*)d_out;

    prep_weights_kernel<<<2068, 256, 0, stream>>>(
        wx_in, wh_in, b_in, wx_r0, wh_r0, b_r0,
        wx_r1, wh_r1, b_r1, wx_out, wh_out, b_out, ws);
    {
        long long total = (long long)BB * TT * LL * CP_IN;
        int blocks = (int)((total + 255) / 256);
        build_features_kernel<<<blocks, 256, 0, stream>>>(
            y_ri, h_ri, evar, no,
            (unsigned short*)(ws + OFF_Z0HI), (unsigned short*)(ws + OFF_Z0LO));
    }

    float* xz    = ws + OFF_XZ;
    float* seq   = ws + OFF_SEQ;
    unsigned short* seqhb = (unsigned short*)(ws + OFF_SEQHI);
    unsigned short* seqlb = (unsigned short*)(ws + OFF_SEQLO);

    const dim3 gIn(LL / 64, BB * TT, 4);    // N=256
    const dim3 gO (LL / 64, BB * TT, 2);    // N=128

    // ---- layer in: Cin=297(p320) -> F=64
    xz_gemm_mfma_kernel<<<gIn, 256, 0, stream>>>(
        (unsigned short*)(ws + OFF_Z0HI), (unsigned short*)(ws + OFF_Z0LO), CP_IN,
        wu + U_WBIN_HI, wu + U_WBIN_LO, ws + OFF_BIN, xz, 256);
    lstm_scan_kernel<64, false, false><<<NBLK, 256, 0, stream>>>(
        xz, wu + U_WHTIN, seq, seqhb, seqlb, nullptr);

    // ---- layer r0 (+residual, in-place on seq)
    xz_gemm_mfma_kernel<<<gIn, 256, 0, stream>>>(
        seqhb, seqlb, 64, wu + U_WBR0_HI, wu + U_WBR0_LO, ws + OFF_BR0, xz, 256);
    lstm_scan_kernel<64, true, false><<<NBLK, 256, 0, stream>>>(
        xz, wu + U_WHTR0, seq, seqhb, seqlb, nullptr);

    // ---- layer r1 (+residual, in-place on seq)
    xz_gemm_mfma_kernel<<<gIn, 256, 0, stream>>>(
        seqhb, seqlb, 64, wu + U_WBR1_HI, wu + U_WBR1_LO, ws + OFF_BR1, xz, 256);
    lstm_scan_kernel<64, true, false><<<NBLK, 256, 0, stream>>>(
        xz, wu + U_WHTR1, seq, seqhb, seqlb, nullptr);

    // ---- layer out: F=32, writes d_out (f32, transposed layout)
    xz_gemm_mfma_kernel<<<gO, 256, 0, stream>>>(
        seqhb, seqlb, 64, wu + U_WBOUT_HI, wu + U_WBOUT_LO, ws + OFF_BOUT, xz, 128);
    lstm_scan_kernel<32, false, true><<<NBLK, 128, 0, stream>>>(
        xz, wu + U_WHTOUT, nullptr, nullptr, nullptr, dout);
}